// Round 2
// baseline (1137.366 us; speedup 1.0000x reference)
//
#include <hip/hip_runtime.h>
#include <hip/hip_bf16.h>

#define BS 16
#define SEQ 4096
#define DIM 64
#define NH 8
#define CL 128
#define NC (SEQ/CL)       // 32
#define NPAIR (NH*BS)     // 128
#define CHK 16            // d-chunk size for QK staging
#define SSTR 20           // staging row stride (floats): 16 + 4 pad, float4-aligned
#define PCH_STR 36        // P-chunk row stride (floats)
#define VT_STR 132        // transposed-V row stride (floats)

__device__ __forceinline__ float dot4(float4 a, float4 b) {
    return a.x*b.x + a.y*b.y + a.z*b.z + a.w*b.w;
}

// ---------------- norms + per-batch max(norm^2) ----------------
__global__ __launch_bounds__(256) void norms_kernel(const float* __restrict__ q,
        const float* __restrict__ k, float* __restrict__ qn2, float* __restrict__ kn2,
        unsigned int* __restrict__ M2bits) {
    int blk = blockIdx.x;
    const int qblocks = BS*SEQ/64;
    bool is_q = blk < qblocks;
    int rowbase = (is_q ? blk : blk - qblocks) * 64;
    const float* src = is_q ? q : k;
    float* dst = is_q ? qn2 : kn2;
    int t = threadIdx.x;
    int sub = t & 3;
    int r = rowbase + (t >> 2);
    const float4* row4 = (const float4*)(src + (size_t)r*DIM) + sub*4;
    float s = 0.f;
    #pragma unroll
    for (int c2 = 0; c2 < 4; ++c2) {
        float4 vv = row4[c2];
        s += vv.x*vv.x + vv.y*vv.y + vv.z*vv.z + vv.w*vv.w;
    }
    s += __shfl_xor(s, 1);
    s += __shfl_xor(s, 2);
    if (sub == 0) dst[r] = s;
    __shared__ float red[256];
    red[t] = s;
    __syncthreads();
    #pragma unroll
    for (int o = 128; o > 0; o >>= 1) {
        if (t < o) red[t] = fmaxf(red[t], red[t + o]);
        __syncthreads();
    }
    if (t == 0) atomicMax(&M2bits[r / SEQ], __float_as_uint(red[0]));
}

// ---------------- E2LSH hashes ----------------
__global__ __launch_bounds__(256) void hash_kernel(const float* __restrict__ q,
        const float* __restrict__ k, const float* __restrict__ qn2,
        const float* __restrict__ kn2, const unsigned int* __restrict__ M2bits,
        const float* __restrict__ alpha, const float* __restrict__ beta,
        float* __restrict__ qh, float* __restrict__ kh) {
    int t = threadIdx.x;
    int sub = t & 3;
    int r = blockIdx.x * 64 + (t >> 2);
    const float4* q4 = (const float4*)(q + (size_t)r*DIM) + sub*4;
    const float4* k4 = (const float4*)(k + (size_t)r*DIM) + sub*4;
    float qa[NH], ka[NH];
    #pragma unroll
    for (int h = 0; h < NH; ++h) { qa[h] = 0.f; ka[h] = 0.f; }
    #pragma unroll
    for (int c2 = 0; c2 < 4; ++c2) {
        int d0 = sub*16 + c2*4;
        float4 qv = q4[c2], kv = k4[c2];
        #pragma unroll
        for (int h = 0; h < NH; ++h) {
            float a0 = alpha[(d0+0)*NH+h], a1 = alpha[(d0+1)*NH+h];
            float a2 = alpha[(d0+2)*NH+h], a3 = alpha[(d0+3)*NH+h];
            qa[h] += qv.x*a0 + qv.y*a1 + qv.z*a2 + qv.w*a3;
            ka[h] += kv.x*a0 + kv.y*a1 + kv.z*a2 + kv.w*a3;
        }
    }
    #pragma unroll
    for (int h = 0; h < NH; ++h) {
        qa[h] += __shfl_xor(qa[h], 1); qa[h] += __shfl_xor(qa[h], 2);
        ka[h] += __shfl_xor(ka[h], 1); ka[h] += __shfl_xor(ka[h], 2);
    }
    if (sub == 0) {
        int b = r / SEQ;
        float m2 = __uint_as_float(M2bits[b]);
        float qe = sqrtf(fmaxf(m2 - qn2[r], 0.f));
        float ke = sqrtf(fmaxf(m2 - kn2[r], 0.f));
        #pragma unroll
        for (int h = 0; h < NH; ++h) {
            qh[(size_t)h*BS*SEQ + r] = qa[h] + qe*alpha[DIM*NH + h] + beta[h];
            kh[(size_t)h*BS*SEQ + r] = ka[h] + ke*alpha[(DIM+1)*NH + h] + beta[h];
        }
    }
}

// ---------------- stable bitonic argsort (4096 per block) ----------------
__global__ __launch_bounds__(512) void sort_kernel(const float* __restrict__ qh,
        const float* __restrict__ kh, int* __restrict__ qpos, int* __restrict__ kpos) {
    __shared__ float sh[SEQ];
    __shared__ int si[SEQ];
    int blk = blockIdx.x;
    const float* src; int* dst;
    if (blk < NPAIR) { src = qh + (size_t)blk*SEQ; dst = qpos + (size_t)blk*SEQ; }
    else { src = kh + (size_t)(blk - NPAIR)*SEQ; dst = kpos + (size_t)(blk - NPAIR)*SEQ; }
    int t = threadIdx.x;
    for (int i = t; i < SEQ; i += 512) { sh[i] = src[i]; si[i] = i; }
    __syncthreads();
    for (int kk = 2; kk <= SEQ; kk <<= 1) {
        for (int j = kk >> 1; j > 0; j >>= 1) {
            #pragma unroll
            for (int w = 0; w < SEQ/512; ++w) {
                int i = t + w*512;
                int ixj = i ^ j;
                if (ixj > i) {
                    bool up = (i & kk) == 0;
                    float h1 = sh[i], h2 = sh[ixj];
                    int i1 = si[i], i2 = si[ixj];
                    bool gt = (h1 > h2) || (h1 == h2 && i1 > i2);
                    if (gt == up) { sh[i] = h2; sh[ixj] = h1; si[i] = i2; si[ixj] = i1; }
                }
            }
            __syncthreads();
        }
    }
    for (int i = t; i < SEQ; i += 512) dst[i] = si[i];
}

// ---------------- pass 1: per-cluster row logsumexp (chunked staging) --------
__global__ __launch_bounds__(256, 3) void lse_kernel(const float* __restrict__ q,
        const float* __restrict__ k, const int* __restrict__ qpos,
        const int* __restrict__ kpos, float* __restrict__ lse) {
    extern __shared__ float smem[];
    float* stg = smem;                     // 2 * 128 * SSTR = 5120 floats
    int* qp = (int*)(smem + 5120);
    int* kp = qp + CL;
    int blk = blockIdx.x;
    int c = blk % NC;
    int hb = blk / NC;
    int b = hb % BS;
    int t = threadIdx.x;
    size_t posbase = (size_t)hb*SEQ + (size_t)c*CL;
    if (t < CL) qp[t] = qpos[posbase + t];
    else kp[t - CL] = kpos[posbase + (t - CL)];
    int tx = t & 15, ty = t >> 4;
    float acc[8][8] = {};
    for (int dc = 0; dc < DIM; dc += CHK) {
        __syncthreads();     // staging region free (also covers qp/kp on iter 0)
        for (int i = t; i < 1024; i += 256) {
            int which = i >> 9, idx = i & 511;
            int r = idx >> 2, d4 = idx & 3;
            const float* src = which ? k : q;
            const int* pp = which ? kp : qp;
            float4 vv = ((const float4*)(src + ((size_t)b*SEQ + pp[r])*DIM + dc))[d4];
            *(float4*)(stg + which*(CL*SSTR) + r*SSTR + d4*4) = vv;
        }
        __syncthreads();
        for (int d = 0; d < CHK; d += 4) {
            float4 qv[8], kv[8];
            #pragma unroll
            for (int i = 0; i < 8; ++i) qv[i] = *(const float4*)(stg + (ty + 16*i)*SSTR + d);
            #pragma unroll
            for (int j = 0; j < 8; ++j) kv[j] = *(const float4*)(stg + CL*SSTR + (tx + 16*j)*SSTR + d);
            #pragma unroll
            for (int i = 0; i < 8; ++i)
                #pragma unroll
                for (int j = 0; j < 8; ++j)
                    acc[i][j] += dot4(qv[i], kv[j]);
        }
    }
    #pragma unroll
    for (int i = 0; i < 8; ++i) {
        int row = ty + 16*i;
        float m = acc[i][0];
        #pragma unroll
        for (int j = 1; j < 8; ++j) m = fmaxf(m, acc[i][j]);
        #pragma unroll
        for (int o = 1; o < 16; o <<= 1) m = fmaxf(m, __shfl_xor(m, o));
        float ssum = 0.f;
        #pragma unroll
        for (int j = 0; j < 8; ++j) ssum += __expf(acc[i][j] - m);
        #pragma unroll
        for (int o = 1; o < 16; o <<= 1) ssum += __shfl_xor(ssum, o);
        if (tx == 0) lse[(size_t)hb*SEQ + qp[row]] = m + __logf(ssum);
    }
}

// ---------------- Z = logsumexp over hash rounds ----------------
__global__ __launch_bounds__(256) void z_kernel(const float* __restrict__ lse,
        float* __restrict__ Z) {
    int i = blockIdx.x * 256 + threadIdx.x;
    float vals[NH];
    float m = -1e30f;
    #pragma unroll
    for (int h = 0; h < NH; ++h) {
        vals[h] = lse[(size_t)h*BS*SEQ + i];
        m = fmaxf(m, vals[h]);
    }
    float s = 0.f;
    #pragma unroll
    for (int h = 0; h < NH; ++h) s += expf(vals[h] - m);
    Z[i] = m + logf(s);
}

// ------- pass 2: exp(QK^T - Z) @ V, atomic scatter (chunked, 74 KB LDS) ------
__global__ __launch_bounds__(256, 2) void attn_kernel(const float* __restrict__ q,
        const float* __restrict__ k, const float* __restrict__ v,
        const int* __restrict__ qpos, const int* __restrict__ kpos,
        const float* __restrict__ Z, float* __restrict__ out) {
    extern __shared__ float smem[];
    float* stg = smem;                 // 5120 floats: Q-chunk + K-chunk
    float* pch = smem + 5120;          // 4608 floats: 128 x PCH_STR P-chunk
    float* vtb = smem + 9728;          // 8448 floats: 64 x VT_STR transposed V
    int* qp = (int*)(smem + 18176);
    int* kp = qp + CL;
    float* zq = (float*)(kp + CL);     // 128 floats; total 18560 floats = 74240 B
    int blk = blockIdx.x;
    int c = blk % NC;
    int hb = blk / NC;
    int b = hb % BS;
    int t = threadIdx.x;
    size_t posbase = (size_t)hb*SEQ + (size_t)c*CL;
    if (t < CL) qp[t] = qpos[posbase + t];
    else kp[t - CL] = kpos[posbase + (t - CL)];
    __syncthreads();
    if (t < CL) zq[t] = Z[(size_t)b*SEQ + qp[t]];
    // stage V transposed: vtb[dv][c] = V[kp[c]][dv]
    for (int i = t; i < CL*16; i += 256) {
        int r = i >> 4, d4 = i & 15;
        float4 vv = ((const float4*)(v + ((size_t)b*SEQ + kp[r])*DIM))[d4];
        vtb[(4*d4 + 0)*VT_STR + r] = vv.x;
        vtb[(4*d4 + 1)*VT_STR + r] = vv.y;
        vtb[(4*d4 + 2)*VT_STR + r] = vv.z;
        vtb[(4*d4 + 3)*VT_STR + r] = vv.w;
    }
    int tx = t & 15, ty = t >> 4;
    float acc[8][8] = {};
    for (int dc = 0; dc < DIM; dc += CHK) {
        __syncthreads();   // staging region free from previous chunk's readers
        for (int i = t; i < 1024; i += 256) {
            int which = i >> 9, idx = i & 511;
            int r = idx >> 2, d4 = idx & 3;
            const float* src = which ? k : q;
            const int* pp = which ? kp : qp;
            float4 vv = ((const float4*)(src + ((size_t)b*SEQ + pp[r])*DIM + dc))[d4];
            *(float4*)(stg + which*(CL*SSTR) + r*SSTR + d4*4) = vv;
        }
        __syncthreads();
        for (int d = 0; d < CHK; d += 4) {
            float4 qv[8], kv[8];
            #pragma unroll
            for (int i = 0; i < 8; ++i) qv[i] = *(const float4*)(stg + (ty + 16*i)*SSTR + d);
            #pragma unroll
            for (int j = 0; j < 8; ++j) kv[j] = *(const float4*)(stg + CL*SSTR + (tx + 16*j)*SSTR + d);
            #pragma unroll
            for (int i = 0; i < 8; ++i)
                #pragma unroll
                for (int j = 0; j < 8; ++j)
                    acc[i][j] += dot4(qv[i], kv[j]);
        }
    }
    #pragma unroll
    for (int i = 0; i < 8; ++i) {
        float zr = zq[ty + 16*i];
        #pragma unroll
        for (int j = 0; j < 8; ++j) acc[i][j] = __expf(acc[i][j] - zr);
    }
    float o[8][4] = {};
    // PV in 4 k-chunks of 32, P round-trips through a small LDS chunk buffer
    for (int pc = 0; pc < 4; ++pc) {
        __syncthreads();   // pch free from previous chunk's readers
        #pragma unroll
        for (int i = 0; i < 8; ++i) {
            pch[(ty + 16*i)*PCH_STR + tx]      = acc[i][2*pc];
            pch[(ty + 16*i)*PCH_STR + tx + 16] = acc[i][2*pc + 1];
        }
        __syncthreads();
        #pragma unroll
        for (int kkl = 0; kkl < 32; kkl += 4) {
            int kk = pc*32 + kkl;
            float4 pv[8], vt4[4];
            #pragma unroll
            for (int i = 0; i < 8; ++i) pv[i] = *(const float4*)(pch + (ty + 16*i)*PCH_STR + kkl);
            #pragma unroll
            for (int jj = 0; jj < 4; ++jj) vt4[jj] = *(const float4*)(vtb + (tx + 16*jj)*VT_STR + kk);
            #pragma unroll
            for (int i = 0; i < 8; ++i)
                #pragma unroll
                for (int jj = 0; jj < 4; ++jj)
                    o[i][jj] += dot4(pv[i], vt4[jj]);
        }
    }
    #pragma unroll
    for (int i = 0; i < 8; ++i) {
        size_t orow = ((size_t)b*SEQ + qp[ty + 16*i])*DIM;
        #pragma unroll
        for (int jj = 0; jj < 4; ++jj)
            atomicAdd(out + orow + tx + 16*jj, o[i][jj]);
    }
}

extern "C" void kernel_launch(void* const* d_in, const int* in_sizes, int n_in,
                              void* d_out, int out_size, void* d_ws, size_t ws_size,
                              hipStream_t stream) {
    const float* q     = (const float*)d_in[0];
    const float* k     = (const float*)d_in[1];
    const float* v     = (const float*)d_in[2];
    const float* alpha = (const float*)d_in[3];
    const float* beta  = (const float*)d_in[4];
    float* out = (float*)d_out;

    float* ws   = (float*)d_ws;
    float* M2   = ws;                        // 16 (padded to 64)
    float* qn2  = ws + 64;                   // BS*SEQ
    float* kn2  = qn2 + BS*SEQ;              // BS*SEQ
    float* qh   = kn2 + BS*SEQ;              // NH*BS*SEQ
    float* kh   = qh + (size_t)NH*BS*SEQ;    // NH*BS*SEQ
    int*   qpos = (int*)(kh + (size_t)NH*BS*SEQ);  // NH*BS*SEQ
    int*   kpos = qpos + (size_t)NH*BS*SEQ;        // NH*BS*SEQ
    float* lse  = (float*)(kpos + (size_t)NH*BS*SEQ); // NH*BS*SEQ
    float* Z    = lse + (size_t)NH*BS*SEQ;         // BS*SEQ

    hipMemsetAsync(M2, 0, 64*sizeof(float), stream);
    hipMemsetAsync(out, 0, (size_t)out_size*sizeof(float), stream);

    norms_kernel<<<2*BS*SEQ/64, 256, 0, stream>>>(q, k, qn2, kn2, (unsigned int*)M2);
    hash_kernel<<<BS*SEQ/64, 256, 0, stream>>>(q, k, qn2, kn2, (const unsigned int*)M2,
                                               alpha, beta, qh, kh);
    sort_kernel<<<2*NPAIR, 512, 0, stream>>>(qh, kh, qpos, kpos);

    const int lse_lds  = (2*CL*SSTR + 2*CL)*sizeof(float);               // 21504 B
    const int attn_lds = (2*CL*SSTR + CL*PCH_STR + DIM*VT_STR + 3*CL)*sizeof(float); // 74240 B
    lse_kernel<<<NH*BS*NC, 256, lse_lds, stream>>>(q, k, qpos, kpos, lse);
    z_kernel<<<BS*SEQ/256, 256, 0, stream>>>(lse, Z);
    attn_kernel<<<NH*BS*NC, 256, attn_lds, stream>>>(q, k, v, qpos, kpos, Z, out);
}

// Round 3
// 755.968 us; speedup vs baseline: 1.5045x; 1.5045x over previous
//
#include <hip/hip_runtime.h>
#include <hip/hip_bf16.h>

#define BS 16
#define SEQ 4096
#define DIM 64
#define NH 8
#define CL 128
#define NC (SEQ/CL)       // 32
#define NPAIR (NH*BS)     // 128
#define QSTR 68           // padded LDS row stride (floats), 272B
#define PSTR 132          // P-buffer stride (floats)
#define TLDS_Q (CL*QSTR)  // 8704 floats per staged tile

__device__ __forceinline__ float dot4(float4 a, float4 b) {
    return a.x*b.x + a.y*b.y + a.z*b.z + a.w*b.w;
}

// ---------------- norms + per-batch max(norm^2) ----------------
__global__ __launch_bounds__(256) void norms_kernel(const float* __restrict__ q,
        const float* __restrict__ k, float* __restrict__ qn2, float* __restrict__ kn2,
        unsigned int* __restrict__ M2bits) {
    int blk = blockIdx.x;
    const int qblocks = BS*SEQ/64;
    bool is_q = blk < qblocks;
    int rowbase = (is_q ? blk : blk - qblocks) * 64;
    const float* src = is_q ? q : k;
    float* dst = is_q ? qn2 : kn2;
    int t = threadIdx.x;
    int sub = t & 3;
    int r = rowbase + (t >> 2);
    const float4* row4 = (const float4*)(src + (size_t)r*DIM) + sub*4;
    float s = 0.f;
    #pragma unroll
    for (int c2 = 0; c2 < 4; ++c2) {
        float4 vv = row4[c2];
        s += vv.x*vv.x + vv.y*vv.y + vv.z*vv.z + vv.w*vv.w;
    }
    s += __shfl_xor(s, 1);
    s += __shfl_xor(s, 2);
    if (sub == 0) dst[r] = s;
    __shared__ float red[256];
    red[t] = s;
    __syncthreads();
    #pragma unroll
    for (int o = 128; o > 0; o >>= 1) {
        if (t < o) red[t] = fmaxf(red[t], red[t + o]);
        __syncthreads();
    }
    if (t == 0) atomicMax(&M2bits[r / SEQ], __float_as_uint(red[0]));
}

// ---------------- E2LSH hashes ----------------
__global__ __launch_bounds__(256) void hash_kernel(const float* __restrict__ q,
        const float* __restrict__ k, const float* __restrict__ qn2,
        const float* __restrict__ kn2, const unsigned int* __restrict__ M2bits,
        const float* __restrict__ alpha, const float* __restrict__ beta,
        float* __restrict__ qh, float* __restrict__ kh) {
    int t = threadIdx.x;
    int sub = t & 3;
    int r = blockIdx.x * 64 + (t >> 2);
    const float4* q4 = (const float4*)(q + (size_t)r*DIM) + sub*4;
    const float4* k4 = (const float4*)(k + (size_t)r*DIM) + sub*4;
    float qa[NH], ka[NH];
    #pragma unroll
    for (int h = 0; h < NH; ++h) { qa[h] = 0.f; ka[h] = 0.f; }
    #pragma unroll
    for (int c2 = 0; c2 < 4; ++c2) {
        int d0 = sub*16 + c2*4;
        float4 qv = q4[c2], kv = k4[c2];
        #pragma unroll
        for (int h = 0; h < NH; ++h) {
            float a0 = alpha[(d0+0)*NH+h], a1 = alpha[(d0+1)*NH+h];
            float a2 = alpha[(d0+2)*NH+h], a3 = alpha[(d0+3)*NH+h];
            qa[h] += qv.x*a0 + qv.y*a1 + qv.z*a2 + qv.w*a3;
            ka[h] += kv.x*a0 + kv.y*a1 + kv.z*a2 + kv.w*a3;
        }
    }
    #pragma unroll
    for (int h = 0; h < NH; ++h) {
        qa[h] += __shfl_xor(qa[h], 1); qa[h] += __shfl_xor(qa[h], 2);
        ka[h] += __shfl_xor(ka[h], 1); ka[h] += __shfl_xor(ka[h], 2);
    }
    if (sub == 0) {
        int b = r / SEQ;
        float m2 = __uint_as_float(M2bits[b]);
        float qe = sqrtf(fmaxf(m2 - qn2[r], 0.f));
        float ke = sqrtf(fmaxf(m2 - kn2[r], 0.f));
        #pragma unroll
        for (int h = 0; h < NH; ++h) {
            qh[(size_t)h*BS*SEQ + r] = qa[h] + qe*alpha[DIM*NH + h] + beta[h];
            kh[(size_t)h*BS*SEQ + r] = ka[h] + ke*alpha[(DIM+1)*NH + h] + beta[h];
        }
    }
}

// ---------------- stable bitonic argsort (4096 per block) ----------------
__global__ __launch_bounds__(512) void sort_kernel(const float* __restrict__ qh,
        const float* __restrict__ kh, int* __restrict__ qpos, int* __restrict__ kpos) {
    __shared__ float sh[SEQ];
    __shared__ int si[SEQ];
    int blk = blockIdx.x;
    const float* src; int* dst;
    if (blk < NPAIR) { src = qh + (size_t)blk*SEQ; dst = qpos + (size_t)blk*SEQ; }
    else { src = kh + (size_t)(blk - NPAIR)*SEQ; dst = kpos + (size_t)(blk - NPAIR)*SEQ; }
    int t = threadIdx.x;
    for (int i = t; i < SEQ; i += 512) { sh[i] = src[i]; si[i] = i; }
    __syncthreads();
    for (int kk = 2; kk <= SEQ; kk <<= 1) {
        for (int j = kk >> 1; j > 0; j >>= 1) {
            #pragma unroll
            for (int w = 0; w < SEQ/512; ++w) {
                int i = t + w*512;
                int ixj = i ^ j;
                if (ixj > i) {
                    bool up = (i & kk) == 0;
                    float h1 = sh[i], h2 = sh[ixj];
                    int i1 = si[i], i2 = si[ixj];
                    bool gt = (h1 > h2) || (h1 == h2 && i1 > i2);
                    if (gt == up) { sh[i] = h2; sh[ixj] = h1; si[i] = i2; si[ixj] = i1; }
                }
            }
            __syncthreads();
        }
    }
    for (int i = t; i < SEQ; i += 512) dst[i] = si[i];
}

// ---- pass 1: per-cluster row logsumexp (full staging, 512 thr, 2 blk/CU) ----
__global__ __launch_bounds__(512) void lse_kernel(const float* __restrict__ q,
        const float* __restrict__ k, const int* __restrict__ qpos,
        const int* __restrict__ kpos, float* __restrict__ lse) {
    extern __shared__ float smem[];
    float* sq = smem;
    float* sk = smem + TLDS_Q;
    int* qp = (int*)(smem + 2*TLDS_Q);
    int* kp = qp + CL;
    int blk = blockIdx.x;
    int c = blk % NC;
    int hb = blk / NC;
    int b = hb % BS;
    int t = threadIdx.x;
    size_t posbase = (size_t)hb*SEQ + (size_t)c*CL;
    if (t < CL) qp[t] = qpos[posbase + t];
    else if (t < 2*CL) kp[t - CL] = kpos[posbase + (t - CL)];
    __syncthreads();
    for (int i = t; i < 2*CL*16; i += 512) {
        int idx = i & (CL*16 - 1);
        int r = idx >> 4, d4 = idx & 15;
        if (i < CL*16) {
            float4 vv = ((const float4*)(q + ((size_t)b*SEQ + qp[r])*DIM))[d4];
            *(float4*)(sq + r*QSTR + d4*4) = vv;
        } else {
            float4 vv = ((const float4*)(k + ((size_t)b*SEQ + kp[r])*DIM))[d4];
            *(float4*)(sk + r*QSTR + d4*4) = vv;
        }
    }
    __syncthreads();
    int tx = t & 31, ty = t >> 5;   // 16 x 32 thread grid, 8x4 tile
    float acc[8][4] = {};
    for (int d = 0; d < DIM; d += 4) {
        float4 qv[8], kv[4];
        #pragma unroll
        for (int i = 0; i < 8; ++i) qv[i] = *(const float4*)(sq + (ty + 16*i)*QSTR + d);
        #pragma unroll
        for (int j = 0; j < 4; ++j) kv[j] = *(const float4*)(sk + (tx + 32*j)*QSTR + d);
        #pragma unroll
        for (int i = 0; i < 8; ++i)
            #pragma unroll
            for (int j = 0; j < 4; ++j)
                acc[i][j] += dot4(qv[i], kv[j]);
    }
    #pragma unroll
    for (int i = 0; i < 8; ++i) {
        int row = ty + 16*i;
        float m = acc[i][0];
        #pragma unroll
        for (int j = 1; j < 4; ++j) m = fmaxf(m, acc[i][j]);
        #pragma unroll
        for (int o = 1; o < 32; o <<= 1) m = fmaxf(m, __shfl_xor(m, o));
        float ssum = 0.f;
        #pragma unroll
        for (int j = 0; j < 4; ++j) ssum += __expf(acc[i][j] - m);
        #pragma unroll
        for (int o = 1; o < 32; o <<= 1) ssum += __shfl_xor(ssum, o);
        if (tx == 0) lse[(size_t)hb*SEQ + qp[row]] = m + __logf(ssum);
    }
}

// ---------------- Z = logsumexp over hash rounds ----------------
__global__ __launch_bounds__(256) void z_kernel(const float* __restrict__ lse,
        float* __restrict__ Z) {
    int i = blockIdx.x * 256 + threadIdx.x;
    float vals[NH];
    float m = -1e30f;
    #pragma unroll
    for (int h = 0; h < NH; ++h) {
        vals[h] = lse[(size_t)h*BS*SEQ + i];
        m = fmaxf(m, vals[h]);
    }
    float s = 0.f;
    #pragma unroll
    for (int h = 0; h < NH; ++h) s += expf(vals[h] - m);
    Z[i] = m + logf(s);
}

// --- pass 2: exp(QK^T - Z) @ V, atomic scatter (R1 memory layout, 512 thr) ---
__global__ __launch_bounds__(512) void attn_kernel(const float* __restrict__ q,
        const float* __restrict__ k, const float* __restrict__ v,
        const int* __restrict__ qpos, const int* __restrict__ kpos,
        const float* __restrict__ Z, float* __restrict__ out) {
    extern __shared__ float smem[];
    float* sq = smem;
    float* sv = smem + 2*TLDS_Q;
    int* qp = (int*)(smem + 3*TLDS_Q);
    int* kp = qp + CL;
    float* zq = (float*)(kp + CL);
    float* pbuf = smem;  // overlays sq+sk after QK phase (16896 <= 17408 floats)
    int blk = blockIdx.x;
    int c = blk % NC;
    int hb = blk / NC;
    int b = hb % BS;
    int t = threadIdx.x;
    size_t posbase = (size_t)hb*SEQ + (size_t)c*CL;
    if (t < CL) qp[t] = qpos[posbase + t];
    else if (t < 2*CL) kp[t - CL] = kpos[posbase + (t - CL)];
    __syncthreads();
    if (t < CL) zq[t] = Z[(size_t)b*SEQ + qp[t]];
    for (int i = t; i < 3*CL*16; i += 512) {
        int idx = i & (CL*16 - 1);
        int r = idx >> 4, d4 = idx & 15;
        int which = i >> 11;
        const float* src = (which == 0) ? (q + ((size_t)b*SEQ + qp[r])*DIM)
                         : (which == 1) ? (k + ((size_t)b*SEQ + kp[r])*DIM)
                                        : (v + ((size_t)b*SEQ + kp[r])*DIM);
        float4 vv = ((const float4*)src)[d4];
        *(float4*)(smem + which*TLDS_Q + r*QSTR + d4*4) = vv;
    }
    __syncthreads();
    int tx = t & 31, ty = t >> 5;   // 16 x 32 grid, 8x4 QK tile
    float acc[8][4] = {};
    {
        const float* sk = smem + TLDS_Q;
        for (int d = 0; d < DIM; d += 4) {
            float4 qv[8], kv[4];
            #pragma unroll
            for (int i = 0; i < 8; ++i) qv[i] = *(const float4*)(sq + (ty + 16*i)*QSTR + d);
            #pragma unroll
            for (int j = 0; j < 4; ++j) kv[j] = *(const float4*)(sk + (tx + 32*j)*QSTR + d);
            #pragma unroll
            for (int i = 0; i < 8; ++i)
                #pragma unroll
                for (int j = 0; j < 4; ++j)
                    acc[i][j] += dot4(qv[i], kv[j]);
        }
    }
    #pragma unroll
    for (int i = 0; i < 8; ++i) {
        float zr = zq[ty + 16*i];
        #pragma unroll
        for (int j = 0; j < 4; ++j) acc[i][j] = __expf(acc[i][j] - zr);
    }
    __syncthreads();  // all threads done reading sq/sk
    #pragma unroll
    for (int i = 0; i < 8; ++i)
        #pragma unroll
        for (int j = 0; j < 4; ++j)
            pbuf[(ty + 16*i)*PSTR + tx + 32*j] = acc[i][j];
    __syncthreads();
    float o[8][2] = {};
    for (int kk = 0; kk < CL; kk += 4) {
        float4 pv[8];
        #pragma unroll
        for (int i = 0; i < 8; ++i) pv[i] = *(const float4*)(pbuf + (ty + 16*i)*PSTR + kk);
        float sb[4][2];
        #pragma unroll
        for (int kq = 0; kq < 4; ++kq)
            #pragma unroll
            for (int jj = 0; jj < 2; ++jj) sb[kq][jj] = sv[(kk + kq)*QSTR + tx + 32*jj];
        #pragma unroll
        for (int i = 0; i < 8; ++i)
            #pragma unroll
            for (int jj = 0; jj < 2; ++jj)
                o[i][jj] += pv[i].x*sb[0][jj] + pv[i].y*sb[1][jj]
                          + pv[i].z*sb[2][jj] + pv[i].w*sb[3][jj];
    }
    #pragma unroll
    for (int i = 0; i < 8; ++i) {
        size_t orow = ((size_t)b*SEQ + qp[ty + 16*i])*DIM;
        #pragma unroll
        for (int jj = 0; jj < 2; ++jj)
            atomicAdd(out + orow + tx + 32*jj, o[i][jj]);
    }
}

extern "C" void kernel_launch(void* const* d_in, const int* in_sizes, int n_in,
                              void* d_out, int out_size, void* d_ws, size_t ws_size,
                              hipStream_t stream) {
    const float* q     = (const float*)d_in[0];
    const float* k     = (const float*)d_in[1];
    const float* v     = (const float*)d_in[2];
    const float* alpha = (const float*)d_in[3];
    const float* beta  = (const float*)d_in[4];
    float* out = (float*)d_out;

    float* ws   = (float*)d_ws;
    float* M2   = ws;                        // 16 (padded to 64)
    float* qn2  = ws + 64;                   // BS*SEQ
    float* kn2  = qn2 + BS*SEQ;              // BS*SEQ
    float* qh   = kn2 + BS*SEQ;              // NH*BS*SEQ
    float* kh   = qh + (size_t)NH*BS*SEQ;    // NH*BS*SEQ
    int*   qpos = (int*)(kh + (size_t)NH*BS*SEQ);  // NH*BS*SEQ
    int*   kpos = qpos + (size_t)NH*BS*SEQ;        // NH*BS*SEQ
    float* lse  = (float*)(kpos + (size_t)NH*BS*SEQ); // NH*BS*SEQ
    float* Z    = lse + (size_t)NH*BS*SEQ;         // BS*SEQ

    hipMemsetAsync(M2, 0, 64*sizeof(float), stream);
    hipMemsetAsync(out, 0, (size_t)out_size*sizeof(float), stream);

    norms_kernel<<<2*BS*SEQ/64, 256, 0, stream>>>(q, k, qn2, kn2, (unsigned int*)M2);
    hash_kernel<<<BS*SEQ/64, 256, 0, stream>>>(q, k, qn2, kn2, (const unsigned int*)M2,
                                               alpha, beta, qh, kh);
    sort_kernel<<<2*NPAIR, 512, 0, stream>>>(qh, kh, qpos, kpos);

    const int lse_lds  = (2*TLDS_Q + 2*CL)*sizeof(float);          // 70656 B
    const int attn_lds = (3*TLDS_Q + 3*CL)*sizeof(float);          // 105984 B
    lse_kernel<<<NH*BS*NC, 512, lse_lds, stream>>>(q, k, qpos, kpos, lse);
    z_kernel<<<BS*SEQ/256, 256, 0, stream>>>(lse, Z);
    attn_kernel<<<NH*BS*NC, 512, attn_lds, stream>>>(q, k, v, qpos, kpos, Z, out);
}

// Round 5
// 442.347 us; speedup vs baseline: 2.5712x; 1.7090x over previous
//
#include <hip/hip_runtime.h>
#include <hip/hip_bf16.h>

#define BS 16
#define SEQ 4096
#define DIM 64
#define NH 8
#define CL 128
#define NC (SEQ/CL)       // 32
#define NPAIR (NH*BS)     // 128
#define QS2 72            // bf16 LDS row stride for Q/K tiles (144 B, /16)
#define VS2 136           // bf16 LDS row stride for Vt and P (272 B, /16)

typedef __attribute__((ext_vector_type(8))) short bf8_t;   // 8 bf16 (4 VGPR)
typedef __attribute__((ext_vector_type(4))) float f4_t;    // MFMA C/D

__device__ __forceinline__ unsigned short f2bf(float x) {
    union { float f; unsigned u; } a; a.f = x;
    unsigned r = a.u + 0x7FFF + ((a.u >> 16) & 1);
    return (unsigned short)(r >> 16);
}
__device__ __forceinline__ float bf2f(unsigned short h) {
    union { unsigned u; float f; } a; a.u = ((unsigned)h) << 16; return a.f;
}

// ---------------- norms + per-batch max(norm^2) ----------------
__global__ __launch_bounds__(256) void norms_kernel(const float* __restrict__ q,
        const float* __restrict__ k, float* __restrict__ qn2, float* __restrict__ kn2,
        unsigned int* __restrict__ M2bits) {
    int blk = blockIdx.x;
    const int qblocks = BS*SEQ/64;
    bool is_q = blk < qblocks;
    int rowbase = (is_q ? blk : blk - qblocks) * 64;
    const float* src = is_q ? q : k;
    float* dst = is_q ? qn2 : kn2;
    int t = threadIdx.x;
    int sub = t & 3;
    int r = rowbase + (t >> 2);
    const float4* row4 = (const float4*)(src + (size_t)r*DIM) + sub*4;
    float s = 0.f;
    #pragma unroll
    for (int c2 = 0; c2 < 4; ++c2) {
        float4 vv = row4[c2];
        s += vv.x*vv.x + vv.y*vv.y + vv.z*vv.z + vv.w*vv.w;
    }
    s += __shfl_xor(s, 1);
    s += __shfl_xor(s, 2);
    if (sub == 0) dst[r] = s;
    __shared__ float red[256];
    red[t] = s;
    __syncthreads();
    #pragma unroll
    for (int o = 128; o > 0; o >>= 1) {
        if (t < o) red[t] = fmaxf(red[t], red[t + o]);
        __syncthreads();
    }
    if (t == 0) atomicMax(&M2bits[r / SEQ], __float_as_uint(red[0]));
}

// ---------------- E2LSH hashes ----------------
__global__ __launch_bounds__(256) void hash_kernel(const float* __restrict__ q,
        const float* __restrict__ k, const float* __restrict__ qn2,
        const float* __restrict__ kn2, const unsigned int* __restrict__ M2bits,
        const float* __restrict__ alpha, const float* __restrict__ beta,
        float* __restrict__ qh, float* __restrict__ kh) {
    int t = threadIdx.x;
    int sub = t & 3;
    int r = blockIdx.x * 64 + (t >> 2);
    const float4* q4 = (const float4*)(q + (size_t)r*DIM) + sub*4;
    const float4* k4 = (const float4*)(k + (size_t)r*DIM) + sub*4;
    float qa[NH], ka[NH];
    #pragma unroll
    for (int h = 0; h < NH; ++h) { qa[h] = 0.f; ka[h] = 0.f; }
    #pragma unroll
    for (int c2 = 0; c2 < 4; ++c2) {
        int d0 = sub*16 + c2*4;
        float4 qv = q4[c2], kv = k4[c2];
        #pragma unroll
        for (int h = 0; h < NH; ++h) {
            float a0 = alpha[(d0+0)*NH+h], a1 = alpha[(d0+1)*NH+h];
            float a2 = alpha[(d0+2)*NH+h], a3 = alpha[(d0+3)*NH+h];
            qa[h] += qv.x*a0 + qv.y*a1 + qv.z*a2 + qv.w*a3;
            ka[h] += kv.x*a0 + kv.y*a1 + kv.z*a2 + kv.w*a3;
        }
    }
    #pragma unroll
    for (int h = 0; h < NH; ++h) {
        qa[h] += __shfl_xor(qa[h], 1); qa[h] += __shfl_xor(qa[h], 2);
        ka[h] += __shfl_xor(ka[h], 1); ka[h] += __shfl_xor(ka[h], 2);
    }
    if (sub == 0) {
        int b = r / SEQ;
        float m2 = __uint_as_float(M2bits[b]);
        float qe = sqrtf(fmaxf(m2 - qn2[r], 0.f));
        float ke = sqrtf(fmaxf(m2 - kn2[r], 0.f));
        #pragma unroll
        for (int h = 0; h < NH; ++h) {
            qh[(size_t)h*BS*SEQ + r] = qa[h] + qe*alpha[DIM*NH + h] + beta[h];
            kh[(size_t)h*BS*SEQ + r] = ka[h] + ke*alpha[(DIM+1)*NH + h] + beta[h];
        }
    }
}

// ---------------- stable bitonic argsort (4096 per block) ----------------
__global__ __launch_bounds__(512) void sort_kernel(const float* __restrict__ qh,
        const float* __restrict__ kh, int* __restrict__ qpos, int* __restrict__ kpos) {
    __shared__ float sh[SEQ];
    __shared__ int si[SEQ];
    int blk = blockIdx.x;
    const float* src; int* dst;
    if (blk < NPAIR) { src = qh + (size_t)blk*SEQ; dst = qpos + (size_t)blk*SEQ; }
    else { src = kh + (size_t)(blk - NPAIR)*SEQ; dst = kpos + (size_t)(blk - NPAIR)*SEQ; }
    int t = threadIdx.x;
    for (int i = t; i < SEQ; i += 512) { sh[i] = src[i]; si[i] = i; }
    __syncthreads();
    for (int kk = 2; kk <= SEQ; kk <<= 1) {
        for (int j = kk >> 1; j > 0; j >>= 1) {
            #pragma unroll
            for (int w = 0; w < SEQ/512; ++w) {
                int i = t + w*512;
                int ixj = i ^ j;
                if (ixj > i) {
                    bool up = (i & kk) == 0;
                    float h1 = sh[i], h2 = sh[ixj];
                    int i1 = si[i], i2 = si[ixj];
                    bool gt = (h1 > h2) || (h1 == h2 && i1 > i2);
                    if (gt == up) { sh[i] = h2; sh[ixj] = h1; si[i] = i2; si[ixj] = i1; }
                }
            }
            __syncthreads();
        }
    }
    for (int i = t; i < SEQ; i += 512) dst[i] = si[i];
}

// ---- pass 1: row logsumexp via split-bf16 MFMA QK^T ----
__global__ __launch_bounds__(512, 4) void lse_kernel(const float* __restrict__ q,
        const float* __restrict__ k, const int* __restrict__ qpos,
        const int* __restrict__ kpos, float* __restrict__ lse) {
    extern __shared__ char smem[];
    short* qhi = (short*)smem;           // 128*72 shorts = 18432 B
    short* qlo = qhi + 128*QS2;
    short* khi = qlo + 128*QS2;
    short* klo = khi + 128*QS2;          // ends at 73728 B
    int* qp = (int*)(smem + 73728);
    int* kp = qp + CL;                   // total 74752 B
    int blk = blockIdx.x;
    int c = blk & (NC-1);
    int hb = blk / NC;
    int b = hb & (BS-1);
    int t = threadIdx.x, lane = t & 63, w = t >> 6;
    size_t posbase = (size_t)hb*SEQ + (size_t)c*CL;
    if (t < CL) qp[t] = qpos[posbase + t];
    else if (t < 2*CL) kp[t - CL] = kpos[posbase + (t - CL)];
    __syncthreads();
    for (int task = t; task < 4096; task += 512) {
        int which = task >> 11;
        int idx = task & 2047;
        int r = idx >> 4, d4 = idx & 15;
        const int* pp = which ? kp : qp;
        const float* src = which ? k : q;
        float4 vv = ((const float4*)(src + ((size_t)b*SEQ + pp[r])*DIM))[d4];
        ushort4 h, l;
        h.x = f2bf(vv.x); h.y = f2bf(vv.y); h.z = f2bf(vv.z); h.w = f2bf(vv.w);
        l.x = f2bf(vv.x - bf2f(h.x)); l.y = f2bf(vv.y - bf2f(h.y));
        l.z = f2bf(vv.z - bf2f(h.z)); l.w = f2bf(vv.w - bf2f(h.w));
        short* hib = which ? khi : qhi;
        short* lob = which ? klo : qlo;
        *(ushort4*)(hib + r*QS2 + d4*4) = h;
        *(ushort4*)(lob + r*QS2 + d4*4) = l;
    }
    __syncthreads();
    int l15 = lane & 15, lg = lane >> 4;
    f4_t acc[8] = {};
    int arow = (w*16 + l15)*QS2 + lg*8;
    #pragma unroll
    for (int ks = 0; ks < 2; ++ks) {
        bf8_t ah = *(bf8_t*)(qhi + arow + 32*ks);
        bf8_t al = *(bf8_t*)(qlo + arow + 32*ks);
        #pragma unroll
        for (int ct = 0; ct < 8; ++ct) {
            int brow = (ct*16 + l15)*QS2 + lg*8 + 32*ks;
            bf8_t bh = *(bf8_t*)(khi + brow);
            bf8_t bl = *(bf8_t*)(klo + brow);
            acc[ct] = __builtin_amdgcn_mfma_f32_16x16x32_bf16(ah, bh, acc[ct], 0, 0, 0);
            acc[ct] = __builtin_amdgcn_mfma_f32_16x16x32_bf16(al, bh, acc[ct], 0, 0, 0);
            acc[ct] = __builtin_amdgcn_mfma_f32_16x16x32_bf16(ah, bl, acc[ct], 0, 0, 0);
        }
    }
    // row-reduce: row = w*16 + lg*4 + r lives across the 16-lane group (same lg)
    #pragma unroll
    for (int r = 0; r < 4; ++r) {
        float m = acc[0][r];
        #pragma unroll
        for (int ct = 1; ct < 8; ++ct) m = fmaxf(m, acc[ct][r]);
        m = fmaxf(m, __shfl_xor(m, 1)); m = fmaxf(m, __shfl_xor(m, 2));
        m = fmaxf(m, __shfl_xor(m, 4)); m = fmaxf(m, __shfl_xor(m, 8));
        float s = 0.f;
        #pragma unroll
        for (int ct = 0; ct < 8; ++ct) s += __expf(acc[ct][r] - m);
        s += __shfl_xor(s, 1); s += __shfl_xor(s, 2);
        s += __shfl_xor(s, 4); s += __shfl_xor(s, 8);
        if (l15 == 0) lse[(size_t)hb*SEQ + qp[w*16 + lg*4 + r]] = m + __logf(s);
    }
}

// ---------------- Z = logsumexp over hash rounds ----------------
__global__ __launch_bounds__(256) void z_kernel(const float* __restrict__ lse,
        float* __restrict__ Z) {
    int i = blockIdx.x * 256 + threadIdx.x;
    float vals[NH];
    float m = -1e30f;
    #pragma unroll
    for (int h = 0; h < NH; ++h) {
        vals[h] = lse[(size_t)h*BS*SEQ + i];
        m = fmaxf(m, vals[h]);
    }
    float s = 0.f;
    #pragma unroll
    for (int h = 0; h < NH; ++h) s += expf(vals[h] - m);
    Z[i] = m + logf(s);
}

// ---- pass 2: exp(QK^T - Z) @ V via MFMA, atomic scatter ----
__global__ __launch_bounds__(512, 4) void attn_kernel(const float* __restrict__ q,
        const float* __restrict__ k, const float* __restrict__ v,
        const int* __restrict__ qpos, const int* __restrict__ kpos,
        const float* __restrict__ Z, float* __restrict__ out) {
    extern __shared__ char smem[];
    short* qhi = (short*)smem;
    short* qlo = qhi + 128*QS2;
    short* khi = qlo + 128*QS2;
    short* klo = khi + 128*QS2;          // QK region: 73728 B
    int* qp = (int*)(smem + 73728);
    int* kp = qp + CL;
    float* zq = (float*)(kp + CL);       // total 75264 B
    short* vt = (short*)smem;            // phase-2 overlay: 64 x VS2 = 17408 B
    short* pb = (short*)(smem + 17408);  // 128 x VS2 = 34816 B (ends 52224)
    int blk = blockIdx.x;
    int c = blk & (NC-1);
    int hb = blk / NC;
    int b = hb & (BS-1);
    int t = threadIdx.x, lane = t & 63, w = t >> 6;
    size_t posbase = (size_t)hb*SEQ + (size_t)c*CL;

    // T14 async-stage of V: coalesced global->reg now, LDS write after QK phase.
    // wave w owns k-groups {w, w+8}; lane = d. kpos rows are wave-uniform.
    float vr0[8], vr1[8];
    {
        int d = lane;
        #pragma unroll
        for (int j = 0; j < 8; ++j) {
            int r0 = kpos[posbase + w*8 + j];
            int r1 = kpos[posbase + (w+8)*8 + j];
            vr0[j] = v[((size_t)b*SEQ + r0)*DIM + d];
            vr1[j] = v[((size_t)b*SEQ + r1)*DIM + d];
        }
    }
    if (t < CL) qp[t] = qpos[posbase + t];
    else if (t < 2*CL) kp[t - CL] = kpos[posbase + (t - CL)];
    __syncthreads();
    if (t < CL) zq[t] = Z[(size_t)b*SEQ + qp[t]];
    for (int task = t; task < 4096; task += 512) {
        int which = task >> 11;
        int idx = task & 2047;
        int r = idx >> 4, d4 = idx & 15;
        const int* pp = which ? kp : qp;
        const float* src = which ? k : q;
        float4 vv = ((const float4*)(src + ((size_t)b*SEQ + pp[r])*DIM))[d4];
        ushort4 h, l;
        h.x = f2bf(vv.x); h.y = f2bf(vv.y); h.z = f2bf(vv.z); h.w = f2bf(vv.w);
        l.x = f2bf(vv.x - bf2f(h.x)); l.y = f2bf(vv.y - bf2f(h.y));
        l.z = f2bf(vv.z - bf2f(h.z)); l.w = f2bf(vv.w - bf2f(h.w));
        short* hib = which ? khi : qhi;
        short* lob = which ? klo : qlo;
        *(ushort4*)(hib + r*QS2 + d4*4) = h;
        *(ushort4*)(lob + r*QS2 + d4*4) = l;
    }
    __syncthreads();
    int l15 = lane & 15, lg = lane >> 4;
    f4_t acc[8] = {};
    int arow = (w*16 + l15)*QS2 + lg*8;
    #pragma unroll
    for (int ks = 0; ks < 2; ++ks) {
        bf8_t ah = *(bf8_t*)(qhi + arow + 32*ks);
        bf8_t al = *(bf8_t*)(qlo + arow + 32*ks);
        #pragma unroll
        for (int ct = 0; ct < 8; ++ct) {
            int brow = (ct*16 + l15)*QS2 + lg*8 + 32*ks;
            bf8_t bh = *(bf8_t*)(khi + brow);
            bf8_t bl = *(bf8_t*)(klo + brow);
            acc[ct] = __builtin_amdgcn_mfma_f32_16x16x32_bf16(ah, bh, acc[ct], 0, 0, 0);
            acc[ct] = __builtin_amdgcn_mfma_f32_16x16x32_bf16(al, bh, acc[ct], 0, 0, 0);
            acc[ct] = __builtin_amdgcn_mfma_f32_16x16x32_bf16(ah, bl, acc[ct], 0, 0, 0);
        }
    }
    // P = exp(inner - Z), computed in place in acc (f32) to cap VGPR pressure.
    // C/D layout: col = l15 + 16*ct, row = w*16 + lg*4 + r.
    {
        float zr[4];
        #pragma unroll
        for (int r = 0; r < 4; ++r) zr[r] = zq[w*16 + lg*4 + r];
        #pragma unroll
        for (int ct = 0; ct < 8; ++ct)
            #pragma unroll
            for (int r = 0; r < 4; ++r)
                acc[ct][r] = __expf(acc[ct][r] - zr[r]);
    }
    __syncthreads();   // everyone done reading Q/K LDS tiles
    // write Vt (bf16, transposed) and P into the overlay region
    {
        bf8_t pk0, pk1;
        #pragma unroll
        for (int j = 0; j < 8; ++j) { pk0[j] = (short)f2bf(vr0[j]); pk1[j] = (short)f2bf(vr1[j]); }
        *(bf8_t*)(vt + lane*VS2 + w*8)     = pk0;
        *(bf8_t*)(vt + lane*VS2 + (w+8)*8) = pk1;
    }
    #pragma unroll
    for (int ct = 0; ct < 8; ++ct)
        #pragma unroll
        for (int r = 0; r < 4; ++r)
            pb[(w*16 + lg*4 + r)*VS2 + ct*16 + l15] = (short)f2bf(acc[ct][r]);
    __syncthreads();
    // PV: O(16x64 strip) = P(16x128) @ V(128x64)
    f4_t oacc[4] = {};
    #pragma unroll
    for (int ks = 0; ks < 4; ++ks) {
        bf8_t pa = *(bf8_t*)(pb + (w*16 + l15)*VS2 + ks*32 + lg*8);
        #pragma unroll
        for (int ct = 0; ct < 4; ++ct) {
            bf8_t vb = *(bf8_t*)(vt + (ct*16 + l15)*VS2 + ks*32 + lg*8);
            oacc[ct] = __builtin_amdgcn_mfma_f32_16x16x32_bf16(pa, vb, oacc[ct], 0, 0, 0);
        }
    }
    #pragma unroll
    for (int ct = 0; ct < 4; ++ct)
        #pragma unroll
        for (int r = 0; r < 4; ++r) {
            int row = w*16 + lg*4 + r;
            atomicAdd(out + ((size_t)b*SEQ + qp[row])*DIM + ct*16 + l15, oacc[ct][r]);
        }
}

extern "C" void kernel_launch(void* const* d_in, const int* in_sizes, int n_in,
                              void* d_out, int out_size, void* d_ws, size_t ws_size,
                              hipStream_t stream) {
    const float* q     = (const float*)d_in[0];
    const float* k     = (const float*)d_in[1];
    const float* v     = (const float*)d_in[2];
    const float* alpha = (const float*)d_in[3];
    const float* beta  = (const float*)d_in[4];
    float* out = (float*)d_out;

    float* ws   = (float*)d_ws;
    float* M2   = ws;                        // 16 (padded to 64)
    float* qn2  = ws + 64;                   // BS*SEQ
    float* kn2  = qn2 + BS*SEQ;              // BS*SEQ
    float* qh   = kn2 + BS*SEQ;              // NH*BS*SEQ
    float* kh   = qh + (size_t)NH*BS*SEQ;    // NH*BS*SEQ
    int*   qpos = (int*)(kh + (size_t)NH*BS*SEQ);  // NH*BS*SEQ
    int*   kpos = qpos + (size_t)NH*BS*SEQ;        // NH*BS*SEQ
    float* lse  = (float*)(kpos + (size_t)NH*BS*SEQ); // NH*BS*SEQ
    float* Z    = lse + (size_t)NH*BS*SEQ;         // BS*SEQ

    hipMemsetAsync(M2, 0, 64*sizeof(float), stream);
    hipMemsetAsync(out, 0, (size_t)out_size*sizeof(float), stream);

    norms_kernel<<<2*BS*SEQ/64, 256, 0, stream>>>(q, k, qn2, kn2, (unsigned int*)M2);
    hash_kernel<<<BS*SEQ/64, 256, 0, stream>>>(q, k, qn2, kn2, (const unsigned int*)M2,
                                               alpha, beta, qh, kh);
    sort_kernel<<<2*NPAIR, 512, 0, stream>>>(qh, kh, qpos, kpos);

    const int lse_lds  = 73728 + 2*CL*(int)sizeof(int);                       // 74752 B
    const int attn_lds = 73728 + 2*CL*(int)sizeof(int) + CL*(int)sizeof(float); // 75264 B
    lse_kernel<<<NH*BS*NC, 512, lse_lds, stream>>>(q, k, qpos, kpos, lse);
    z_kernel<<<BS*SEQ/256, 256, 0, stream>>>(lse, Z);
    attn_kernel<<<NH*BS*NC, 512, attn_lds, stream>>>(q, k, v, qpos, kpos, Z, out);
}

// Round 7
// 391.964 us; speedup vs baseline: 2.9017x; 1.1285x over previous
//
#include <hip/hip_runtime.h>
#include <hip/hip_bf16.h>

#define BS 16
#define SEQ 4096
#define DIM 64
#define NH 8
#define CL 128
#define NC (SEQ/CL)       // 32
#define NPAIR (NH*BS)     // 128
#define QS2 72            // bf16 LDS row stride for K tiles (144 B, 16B-aligned)
#define VS2 136           // bf16 LDS row stride for Vt (272 B, 16B-aligned)
#define PS 72             // bf16 LDS row stride for P half-buffer (64 cols + 8 pad)

typedef __attribute__((ext_vector_type(8))) short bf8_t;   // 8 bf16 (4 VGPR)
typedef __attribute__((ext_vector_type(4))) float f4_t;    // MFMA C/D

__device__ __forceinline__ unsigned short f2bf(float x) {
    union { float f; unsigned u; } a; a.f = x;
    unsigned r = a.u + 0x7FFF + ((a.u >> 16) & 1);
    return (unsigned short)(r >> 16);
}
__device__ __forceinline__ float bf2f(unsigned short h) {
    union { unsigned u; float f; } a; a.u = ((unsigned)h) << 16; return a.f;
}
// split 8 fp32 (two float4) into hi/lo bf16 fragments (bit-identical to LDS path)
__device__ __forceinline__ void split8(float4 a, float4 b, bf8_t& hi, bf8_t& lo) {
    float v[8] = {a.x, a.y, a.z, a.w, b.x, b.y, b.z, b.w};
    #pragma unroll
    for (int j = 0; j < 8; ++j) {
        unsigned short h = f2bf(v[j]);
        hi[j] = (short)h;
        lo[j] = (short)f2bf(v[j] - bf2f(h));
    }
}

// ---------------- norms + per-batch max(norm^2) ----------------
__global__ __launch_bounds__(256) void norms_kernel(const float* __restrict__ q,
        const float* __restrict__ k, float* __restrict__ qn2, float* __restrict__ kn2,
        unsigned int* __restrict__ M2bits) {
    int blk = blockIdx.x;
    const int qblocks = BS*SEQ/64;
    bool is_q = blk < qblocks;
    int rowbase = (is_q ? blk : blk - qblocks) * 64;
    const float* src = is_q ? q : k;
    float* dst = is_q ? qn2 : kn2;
    int t = threadIdx.x;
    int sub = t & 3;
    int r = rowbase + (t >> 2);
    const float4* row4 = (const float4*)(src + (size_t)r*DIM) + sub*4;
    float s = 0.f;
    #pragma unroll
    for (int c2 = 0; c2 < 4; ++c2) {
        float4 vv = row4[c2];
        s += vv.x*vv.x + vv.y*vv.y + vv.z*vv.z + vv.w*vv.w;
    }
    s += __shfl_xor(s, 1);
    s += __shfl_xor(s, 2);
    if (sub == 0) dst[r] = s;
    __shared__ float red[256];
    red[t] = s;
    __syncthreads();
    #pragma unroll
    for (int o = 128; o > 0; o >>= 1) {
        if (t < o) red[t] = fmaxf(red[t], red[t + o]);
        __syncthreads();
    }
    if (t == 0) atomicMax(&M2bits[r / SEQ], __float_as_uint(red[0]));
}

// ---------------- E2LSH hashes ----------------
__global__ __launch_bounds__(256) void hash_kernel(const float* __restrict__ q,
        const float* __restrict__ k, const float* __restrict__ qn2,
        const float* __restrict__ kn2, const unsigned int* __restrict__ M2bits,
        const float* __restrict__ alpha, const float* __restrict__ beta,
        float* __restrict__ qh, float* __restrict__ kh) {
    int t = threadIdx.x;
    int sub = t & 3;
    int r = blockIdx.x * 64 + (t >> 2);
    const float4* q4 = (const float4*)(q + (size_t)r*DIM) + sub*4;
    const float4* k4 = (const float4*)(k + (size_t)r*DIM) + sub*4;
    float qa[NH], ka[NH];
    #pragma unroll
    for (int h = 0; h < NH; ++h) { qa[h] = 0.f; ka[h] = 0.f; }
    #pragma unroll
    for (int c2 = 0; c2 < 4; ++c2) {
        int d0 = sub*16 + c2*4;
        float4 qv = q4[c2], kv = k4[c2];
        #pragma unroll
        for (int h = 0; h < NH; ++h) {
            float a0 = alpha[(d0+0)*NH+h], a1 = alpha[(d0+1)*NH+h];
            float a2 = alpha[(d0+2)*NH+h], a3 = alpha[(d0+3)*NH+h];
            qa[h] += qv.x*a0 + qv.y*a1 + qv.z*a2 + qv.w*a3;
            ka[h] += kv.x*a0 + kv.y*a1 + kv.z*a2 + kv.w*a3;
        }
    }
    #pragma unroll
    for (int h = 0; h < NH; ++h) {
        qa[h] += __shfl_xor(qa[h], 1); qa[h] += __shfl_xor(qa[h], 2);
        ka[h] += __shfl_xor(ka[h], 1); ka[h] += __shfl_xor(ka[h], 2);
    }
    if (sub == 0) {
        int b = r / SEQ;
        float m2 = __uint_as_float(M2bits[b]);
        float qe = sqrtf(fmaxf(m2 - qn2[r], 0.f));
        float ke = sqrtf(fmaxf(m2 - kn2[r], 0.f));
        #pragma unroll
        for (int h = 0; h < NH; ++h) {
            qh[(size_t)h*BS*SEQ + r] = qa[h] + qe*alpha[DIM*NH + h] + beta[h];
            kh[(size_t)h*BS*SEQ + r] = ka[h] + ke*alpha[(DIM+1)*NH + h] + beta[h];
        }
    }
}

// ---------------- stable bitonic argsort (4096 per block) ----------------
__global__ __launch_bounds__(512) void sort_kernel(const float* __restrict__ qh,
        const float* __restrict__ kh, int* __restrict__ qpos, int* __restrict__ kpos) {
    __shared__ float sh[SEQ];
    __shared__ int si[SEQ];
    int blk = blockIdx.x;
    const float* src; int* dst;
    if (blk < NPAIR) { src = qh + (size_t)blk*SEQ; dst = qpos + (size_t)blk*SEQ; }
    else { src = kh + (size_t)(blk - NPAIR)*SEQ; dst = kpos + (size_t)(blk - NPAIR)*SEQ; }
    int t = threadIdx.x;
    for (int i = t; i < SEQ; i += 512) { sh[i] = src[i]; si[i] = i; }
    __syncthreads();
    for (int kk = 2; kk <= SEQ; kk <<= 1) {
        for (int j = kk >> 1; j > 0; j >>= 1) {
            #pragma unroll
            for (int w = 0; w < SEQ/512; ++w) {
                int i = t + w*512;
                int ixj = i ^ j;
                if (ixj > i) {
                    bool up = (i & kk) == 0;
                    float h1 = sh[i], h2 = sh[ixj];
                    int i1 = si[i], i2 = si[ixj];
                    bool gt = (h1 > h2) || (h1 == h2 && i1 > i2);
                    if (gt == up) { sh[i] = h2; sh[ixj] = h1; si[i] = i2; si[ixj] = i1; }
                }
            }
            __syncthreads();
        }
    }
    for (int i = t; i < SEQ; i += 512) dst[i] = si[i];
}

// ---- pass 1: row logsumexp; Q frags in regs, K hi/lo in LDS (37.9 KB) ----
__global__ __launch_bounds__(512, 6) void lse_kernel(const float* __restrict__ q,
        const float* __restrict__ k, const int* __restrict__ qpos,
        const int* __restrict__ kpos, float* __restrict__ lse) {
    extern __shared__ char smem[];
    short* khi = (short*)smem;           // 128*72*2 = 18432 B
    short* klo = khi + 128*QS2;          // ends 36864
    int* qp = (int*)(smem + 36864);
    int* kp = qp + CL;                   // total 37888 B
    int blk = blockIdx.x;
    int c = blk & (NC-1);
    int hb = blk / NC;
    int b = hb & (BS-1);
    int t = threadIdx.x, lane = t & 63, w = t >> 6;
    int l15 = lane & 15, lg = lane >> 4;
    size_t posbase = (size_t)hb*SEQ + (size_t)c*CL;

    // Q fragments straight from global (own rows per wave); bit-identical split
    int qrow = qpos[posbase + w*16 + l15];
    const float* qsrc = q + ((size_t)b*SEQ + qrow)*DIM + lg*8;
    float4 qv0 = *(const float4*)(qsrc);
    float4 qv1 = *(const float4*)(qsrc + 4);
    float4 qv2 = *(const float4*)(qsrc + 32);
    float4 qv3 = *(const float4*)(qsrc + 36);

    if (t < CL) qp[t] = qpos[posbase + t];
    else if (t < 2*CL) kp[t - CL] = kpos[posbase + (t - CL)];
    __syncthreads();
    for (int task = t; task < 2048; task += 512) {
        int r = task >> 4, d4 = task & 15;
        float4 vv = ((const float4*)(k + ((size_t)b*SEQ + kp[r])*DIM))[d4];
        ushort4 h, l;
        h.x = f2bf(vv.x); h.y = f2bf(vv.y); h.z = f2bf(vv.z); h.w = f2bf(vv.w);
        l.x = f2bf(vv.x - bf2f(h.x)); l.y = f2bf(vv.y - bf2f(h.y));
        l.z = f2bf(vv.z - bf2f(h.z)); l.w = f2bf(vv.w - bf2f(h.w));
        *(ushort4*)(khi + r*QS2 + d4*4) = h;
        *(ushort4*)(klo + r*QS2 + d4*4) = l;
    }
    bf8_t ah[2], al[2];
    split8(qv0, qv1, ah[0], al[0]);
    split8(qv2, qv3, ah[1], al[1]);
    __syncthreads();
    f4_t acc[8] = {};
    #pragma unroll
    for (int ks = 0; ks < 2; ++ks) {
        #pragma unroll
        for (int ct = 0; ct < 8; ++ct) {
            int brow = (ct*16 + l15)*QS2 + lg*8 + 32*ks;
            bf8_t bh = *(bf8_t*)(khi + brow);
            bf8_t bl = *(bf8_t*)(klo + brow);
            acc[ct] = __builtin_amdgcn_mfma_f32_16x16x32_bf16(ah[ks], bh, acc[ct], 0, 0, 0);
            acc[ct] = __builtin_amdgcn_mfma_f32_16x16x32_bf16(al[ks], bh, acc[ct], 0, 0, 0);
            acc[ct] = __builtin_amdgcn_mfma_f32_16x16x32_bf16(ah[ks], bl, acc[ct], 0, 0, 0);
        }
    }
    // row-reduce: row = w*16 + lg*4 + r lives across the 16-lane group
    #pragma unroll
    for (int r = 0; r < 4; ++r) {
        float m = acc[0][r];
        #pragma unroll
        for (int ct = 1; ct < 8; ++ct) m = fmaxf(m, acc[ct][r]);
        m = fmaxf(m, __shfl_xor(m, 1)); m = fmaxf(m, __shfl_xor(m, 2));
        m = fmaxf(m, __shfl_xor(m, 4)); m = fmaxf(m, __shfl_xor(m, 8));
        float s = 0.f;
        #pragma unroll
        for (int ct = 0; ct < 8; ++ct) s += __expf(acc[ct][r] - m);
        s += __shfl_xor(s, 1); s += __shfl_xor(s, 2);
        s += __shfl_xor(s, 4); s += __shfl_xor(s, 8);
        if (l15 == 0) lse[(size_t)hb*SEQ + qp[w*16 + lg*4 + r]] = m + __logf(s);
    }
}

// ---------------- Z = logsumexp over hash rounds ----------------
__global__ __launch_bounds__(256) void z_kernel(const float* __restrict__ lse,
        float* __restrict__ Z) {
    int i = blockIdx.x * 256 + threadIdx.x;
    float vals[NH];
    float m = -1e30f;
    #pragma unroll
    for (int h = 0; h < NH; ++h) {
        vals[h] = lse[(size_t)h*BS*SEQ + i];
        m = fmaxf(m, vals[h]);
    }
    float s = 0.f;
    #pragma unroll
    for (int h = 0; h < NH; ++h) s += expf(vals[h] - m);
    Z[i] = m + logf(s);
}

// ---- pass 2: exp(QK^T - Z) @ V via MFMA; 38.4 KB LDS, halved-P PV ----
__global__ __launch_bounds__(512, 6) void attn_kernel(const float* __restrict__ q,
        const float* __restrict__ k, const float* __restrict__ v,
        const int* __restrict__ qpos, const int* __restrict__ kpos,
        const float* __restrict__ Z, float* __restrict__ out) {
    extern __shared__ char smem[];
    short* khi = (short*)smem;           // QK phase: 36864 B
    short* klo = khi + 128*QS2;
    short* vt = (short*)smem;            // PV overlay: 64 x VS2 x2 = 17408 B
    short* pb = (short*)(smem + 17408);  // 128 x PS x2 = 18432 B (ends 35840)
    int* qp = (int*)(smem + 36864);      // persistent tail
    int* kp = qp + CL;
    float* zq = (float*)(kp + CL);       // total 38400 B
    int blk = blockIdx.x;
    int c = blk & (NC-1);
    int hb = blk / NC;
    int b = hb & (BS-1);
    int t = threadIdx.x, lane = t & 63, w = t >> 6;
    int l15 = lane & 15, lg = lane >> 4;
    size_t posbase = (size_t)hb*SEQ + (size_t)c*CL;

    // Q fragments straight from global (no Q LDS tile)
    int qrow = qpos[posbase + w*16 + l15];
    const float* qsrc = q + ((size_t)b*SEQ + qrow)*DIM + lg*8;
    float4 qv0 = *(const float4*)(qsrc);
    float4 qv1 = *(const float4*)(qsrc + 4);
    float4 qv2 = *(const float4*)(qsrc + 32);
    float4 qv3 = *(const float4*)(qsrc + 36);

    if (t < CL) qp[t] = qpos[posbase + t];
    else if (t < 2*CL) kp[t - CL] = kpos[posbase + (t - CL)];
    __syncthreads();
    if (t < CL) zq[t] = Z[(size_t)b*SEQ + qp[t]];
    for (int task = t; task < 2048; task += 512) {
        int r = task >> 4, d4 = task & 15;
        float4 vv = ((const float4*)(k + ((size_t)b*SEQ + kp[r])*DIM))[d4];
        ushort4 h, l;
        h.x = f2bf(vv.x); h.y = f2bf(vv.y); h.z = f2bf(vv.z); h.w = f2bf(vv.w);
        l.x = f2bf(vv.x - bf2f(h.x)); l.y = f2bf(vv.y - bf2f(h.y));
        l.z = f2bf(vv.z - bf2f(h.z)); l.w = f2bf(vv.w - bf2f(h.w));
        *(ushort4*)(khi + r*QS2 + d4*4) = h;
        *(ushort4*)(klo + r*QS2 + d4*4) = l;
    }
    bf8_t ah[2], al[2];
    split8(qv0, qv1, ah[0], al[0]);
    split8(qv2, qv3, ah[1], al[1]);
    __syncthreads();
    f4_t acc[8] = {};
    #pragma unroll
    for (int ks = 0; ks < 2; ++ks) {
        #pragma unroll
        for (int ct = 0; ct < 8; ++ct) {
            int brow = (ct*16 + l15)*QS2 + lg*8 + 32*ks;
            bf8_t bh = *(bf8_t*)(khi + brow);
            bf8_t bl = *(bf8_t*)(klo + brow);
            acc[ct] = __builtin_amdgcn_mfma_f32_16x16x32_bf16(ah[ks], bh, acc[ct], 0, 0, 0);
            acc[ct] = __builtin_amdgcn_mfma_f32_16x16x32_bf16(al[ks], bh, acc[ct], 0, 0, 0);
            acc[ct] = __builtin_amdgcn_mfma_f32_16x16x32_bf16(ah[ks], bl, acc[ct], 0, 0, 0);
        }
    }
    // P = exp(inner - Z) in place (C/D: col = l15+16ct, row = w*16+lg*4+r)
    {
        float zr[4];
        #pragma unroll
        for (int r = 0; r < 4; ++r) zr[r] = zq[w*16 + lg*4 + r];
        #pragma unroll
        for (int ct = 0; ct < 8; ++ct)
            #pragma unroll
            for (int r = 0; r < 4; ++r)
                acc[ct][r] = __expf(acc[ct][r] - zr[r]);
    }
    __syncthreads();   // K LDS tiles dead; overlay becomes valid
    // V gather (rows wave-uniform via kp, lane = output dim d)
    float vr0[8], vr1[8];
    #pragma unroll
    for (int j = 0; j < 8; ++j) {
        int r0 = kp[w*8 + j];
        int r1 = kp[(w+8)*8 + j];
        vr0[j] = v[((size_t)b*SEQ + r0)*DIM + lane];
        vr1[j] = v[((size_t)b*SEQ + r1)*DIM + lane];
    }
    // P half 0 (k-cols 0..63) while V loads are in flight
    #pragma unroll
    for (int ct = 0; ct < 4; ++ct)
        #pragma unroll
        for (int r = 0; r < 4; ++r)
            pb[(w*16 + lg*4 + r)*PS + ct*16 + l15] = (short)f2bf(acc[ct][r]);
    // Vt write (transposed, bf16)
    {
        bf8_t pk0, pk1;
        #pragma unroll
        for (int j = 0; j < 8; ++j) { pk0[j] = (short)f2bf(vr0[j]); pk1[j] = (short)f2bf(vr1[j]); }
        *(bf8_t*)(vt + lane*VS2 + w*8)     = pk0;
        *(bf8_t*)(vt + lane*VS2 + (w+8)*8) = pk1;
    }
    __syncthreads();
    f4_t oacc[4] = {};
    #pragma unroll
    for (int ks = 0; ks < 2; ++ks) {
        bf8_t pa = *(bf8_t*)(pb + (w*16 + l15)*PS + ks*32 + lg*8);
        #pragma unroll
        for (int n = 0; n < 4; ++n) {
            bf8_t vb = *(bf8_t*)(vt + (n*16 + l15)*VS2 + ks*32 + lg*8);
            oacc[n] = __builtin_amdgcn_mfma_f32_16x16x32_bf16(pa, vb, oacc[n], 0, 0, 0);
        }
    }
    __syncthreads();   // pb half 0 consumed
    // P half 1 (k-cols 64..127)
    #pragma unroll
    for (int ct = 4; ct < 8; ++ct)
        #pragma unroll
        for (int r = 0; r < 4; ++r)
            pb[(w*16 + lg*4 + r)*PS + (ct-4)*16 + l15] = (short)f2bf(acc[ct][r]);
    __syncthreads();
    #pragma unroll
    for (int ks = 2; ks < 4; ++ks) {
        bf8_t pa = *(bf8_t*)(pb + (w*16 + l15)*PS + (ks-2)*32 + lg*8);
        #pragma unroll
        for (int n = 0; n < 4; ++n) {
            bf8_t vb = *(bf8_t*)(vt + (n*16 + l15)*VS2 + ks*32 + lg*8);
            oacc[n] = __builtin_amdgcn_mfma_f32_16x16x32_bf16(pa, vb, oacc[n], 0, 0, 0);
        }
    }
    #pragma unroll
    for (int n = 0; n < 4; ++n)
        #pragma unroll
        for (int r = 0; r < 4; ++r) {
            int row = w*16 + lg*4 + r;
            atomicAdd(out + ((size_t)b*SEQ + qp[row])*DIM + n*16 + l15, oacc[n][r]);
        }
}

extern "C" void kernel_launch(void* const* d_in, const int* in_sizes, int n_in,
                              void* d_out, int out_size, void* d_ws, size_t ws_size,
                              hipStream_t stream) {
    const float* q     = (const float*)d_in[0];
    const float* k     = (const float*)d_in[1];
    const float* v     = (const float*)d_in[2];
    const float* alpha = (const float*)d_in[3];
    const float* beta  = (const float*)d_in[4];
    float* out = (float*)d_out;

    float* ws   = (float*)d_ws;
    float* M2   = ws;                        // 16 (padded to 64)
    float* qn2  = ws + 64;                   // BS*SEQ
    float* kn2  = qn2 + BS*SEQ;              // BS*SEQ
    float* qh   = kn2 + BS*SEQ;              // NH*BS*SEQ
    float* kh   = qh + (size_t)NH*BS*SEQ;    // NH*BS*SEQ
    int*   qpos = (int*)(kh + (size_t)NH*BS*SEQ);  // NH*BS*SEQ
    int*   kpos = qpos + (size_t)NH*BS*SEQ;        // NH*BS*SEQ
    float* lse  = (float*)(kpos + (size_t)NH*BS*SEQ); // NH*BS*SEQ
    float* Z    = lse + (size_t)NH*BS*SEQ;         // BS*SEQ

    hipMemsetAsync(M2, 0, 64*sizeof(float), stream);
    hipMemsetAsync(out, 0, (size_t)out_size*sizeof(float), stream);

    norms_kernel<<<2*BS*SEQ/64, 256, 0, stream>>>(q, k, qn2, kn2, (unsigned int*)M2);
    hash_kernel<<<BS*SEQ/64, 256, 0, stream>>>(q, k, qn2, kn2, (const unsigned int*)M2,
                                               alpha, beta, qh, kh);
    sort_kernel<<<2*NPAIR, 512, 0, stream>>>(qh, kh, qpos, kpos);

    const int lse_lds  = 36864 + 2*CL*(int)sizeof(int);                         // 37888 B
    const int attn_lds = 36864 + 2*CL*(int)sizeof(int) + CL*(int)sizeof(float); // 38400 B
    lse_kernel<<<NH*BS*NC, 512, lse_lds, stream>>>(q, k, qpos, kpos, lse);
    z_kernel<<<BS*SEQ/256, 256, 0, stream>>>(lse, Z);
    attn_kernel<<<NH*BS*NC, 512, attn_lds, stream>>>(q, k, v, qpos, kpos, Z, out);
}

// Round 10
// 369.300 us; speedup vs baseline: 3.0798x; 1.0614x over previous
//
#include <hip/hip_runtime.h>
#include <hip/hip_bf16.h>

#define BS 16
#define SEQ 4096
#define DIM 64
#define NH 8
#define CL 128
#define NC (SEQ/CL)       // 32
#define NPAIR (NH*BS)     // 128
#define QS2 72            // bf16 LDS row stride for K tiles (144 B, 16B-aligned)
#define VS2 136           // bf16 LDS row stride for Vt (272 B, 16B-aligned)
#define PS 72             // bf16 LDS row stride for P half-buffer (64 cols + 8 pad)

typedef __attribute__((ext_vector_type(8))) short bf8_t;   // 8 bf16 (4 VGPR)
typedef __attribute__((ext_vector_type(4))) float f4_t;    // MFMA C/D

__device__ __forceinline__ unsigned short f2bf(float x) {
    union { float f; unsigned u; } a; a.f = x;
    unsigned r = a.u + 0x7FFF + ((a.u >> 16) & 1);
    return (unsigned short)(r >> 16);
}
__device__ __forceinline__ float bf2f(unsigned short h) {
    union { unsigned u; float f; } a; a.u = ((unsigned)h) << 16; return a.f;
}
// split 8 fp32 (two float4) into hi/lo bf16 fragments (bit-identical to LDS path)
__device__ __forceinline__ void split8(float4 a, float4 b, bf8_t& hi, bf8_t& lo) {
    float v[8] = {a.x, a.y, a.z, a.w, b.x, b.y, b.z, b.w};
    #pragma unroll
    for (int j = 0; j < 8; ++j) {
        unsigned short h = f2bf(v[j]);
        hi[j] = (short)h;
        lo[j] = (short)f2bf(v[j] - bf2f(h));
    }
}

// ---------------- norms + per-batch max(norm^2) ----------------
__global__ __launch_bounds__(256) void norms_kernel(const float* __restrict__ q,
        const float* __restrict__ k, float* __restrict__ qn2, float* __restrict__ kn2,
        unsigned int* __restrict__ M2bits) {
    int blk = blockIdx.x;
    const int qblocks = BS*SEQ/64;
    bool is_q = blk < qblocks;
    int rowbase = (is_q ? blk : blk - qblocks) * 64;
    const float* src = is_q ? q : k;
    float* dst = is_q ? qn2 : kn2;
    int t = threadIdx.x;
    int sub = t & 3;
    int r = rowbase + (t >> 2);
    const float4* row4 = (const float4*)(src + (size_t)r*DIM) + sub*4;
    float s = 0.f;
    #pragma unroll
    for (int c2 = 0; c2 < 4; ++c2) {
        float4 vv = row4[c2];
        s += vv.x*vv.x + vv.y*vv.y + vv.z*vv.z + vv.w*vv.w;
    }
    s += __shfl_xor(s, 1);
    s += __shfl_xor(s, 2);
    if (sub == 0) dst[r] = s;
    __shared__ float red[256];
    red[t] = s;
    __syncthreads();
    #pragma unroll
    for (int o = 128; o > 0; o >>= 1) {
        if (t < o) red[t] = fmaxf(red[t], red[t + o]);
        __syncthreads();
    }
    if (t == 0) atomicMax(&M2bits[r / SEQ], __float_as_uint(red[0]));
}

// ---------------- E2LSH hashes ----------------
__global__ __launch_bounds__(256) void hash_kernel(const float* __restrict__ q,
        const float* __restrict__ k, const float* __restrict__ qn2,
        const float* __restrict__ kn2, const unsigned int* __restrict__ M2bits,
        const float* __restrict__ alpha, const float* __restrict__ beta,
        float* __restrict__ qh, float* __restrict__ kh) {
    int t = threadIdx.x;
    int sub = t & 3;
    int r = blockIdx.x * 64 + (t >> 2);
    const float4* q4 = (const float4*)(q + (size_t)r*DIM) + sub*4;
    const float4* k4 = (const float4*)(k + (size_t)r*DIM) + sub*4;
    float qa[NH], ka[NH];
    #pragma unroll
    for (int h = 0; h < NH; ++h) { qa[h] = 0.f; ka[h] = 0.f; }
    #pragma unroll
    for (int c2 = 0; c2 < 4; ++c2) {
        int d0 = sub*16 + c2*4;
        float4 qv = q4[c2], kv = k4[c2];
        #pragma unroll
        for (int h = 0; h < NH; ++h) {
            float a0 = alpha[(d0+0)*NH+h], a1 = alpha[(d0+1)*NH+h];
            float a2 = alpha[(d0+2)*NH+h], a3 = alpha[(d0+3)*NH+h];
            qa[h] += qv.x*a0 + qv.y*a1 + qv.z*a2 + qv.w*a3;
            ka[h] += kv.x*a0 + kv.y*a1 + kv.z*a2 + kv.w*a3;
        }
    }
    #pragma unroll
    for (int h = 0; h < NH; ++h) {
        qa[h] += __shfl_xor(qa[h], 1); qa[h] += __shfl_xor(qa[h], 2);
        ka[h] += __shfl_xor(ka[h], 1); ka[h] += __shfl_xor(ka[h], 2);
    }
    if (sub == 0) {
        int b = r / SEQ;
        float m2 = __uint_as_float(M2bits[b]);
        float qe = sqrtf(fmaxf(m2 - qn2[r], 0.f));
        float ke = sqrtf(fmaxf(m2 - kn2[r], 0.f));
        #pragma unroll
        for (int h = 0; h < NH; ++h) {
            qh[(size_t)h*BS*SEQ + r] = qa[h] + qe*alpha[DIM*NH + h] + beta[h];
            kh[(size_t)h*BS*SEQ + r] = ka[h] + ke*alpha[(DIM+1)*NH + h] + beta[h];
        }
    }
}

// ---- stable bitonic argsort, hybrid register/LDS (4096 per block) ----
__device__ __forceinline__ void ce(float& h1, int& i1, float& h2, int& i2, bool up) {
    bool gt = (h1 > h2) || (h1 == h2 && i1 > i2);
    if (gt == up) {
        float th = h1; h1 = h2; h2 = th;
        int ti = i1; i1 = i2; i2 = ti;
    }
}

__global__ __launch_bounds__(1024) void sort_kernel(const float* __restrict__ qh,
        const float* __restrict__ kh, int* __restrict__ qpos, int* __restrict__ kpos) {
    __shared__ float sh[SEQ];
    __shared__ int si[SEQ];
    int blk = blockIdx.x;
    const float* src; int* dst;
    if (blk < NPAIR) { src = qh + (size_t)blk*SEQ; dst = qpos + (size_t)blk*SEQ; }
    else { src = kh + (size_t)(blk - NPAIR)*SEQ; dst = kpos + (size_t)(blk - NPAIR)*SEQ; }
    int t = threadIdx.x;
    int base = t * 4;

    // load own 4 contiguous elements; k=2 and k=4 levels fully in registers
    float4 hv = *(const float4*)(src + base);
    float h[4] = {hv.x, hv.y, hv.z, hv.w};
    int id[4] = {base, base + 1, base + 2, base + 3};
    ce(h[0], id[0], h[1], id[1], true);    // k=2, j=1: (0,1) up
    ce(h[2], id[2], h[3], id[3], false);   // k=2, j=1: (2,3) down
    bool up4 = (base & 4) == 0;
    ce(h[0], id[0], h[2], id[2], up4);     // k=4, j=2
    ce(h[1], id[1], h[3], id[3], up4);
    ce(h[0], id[0], h[1], id[1], up4);     // k=4, j=1
    ce(h[2], id[2], h[3], id[3], up4);
    *(float4*)(sh + base) = make_float4(h[0], h[1], h[2], h[3]);
    *(int4*)(si + base) = make_int4(id[0], id[1], id[2], id[3]);
    __syncthreads();

    for (int k = 8; k <= SEQ; k <<= 1) {
        // cross-chunk steps (j >= 4) in LDS
        for (int j = k >> 1; j >= 4; j >>= 1) {
            #pragma unroll
            for (int w = 0; w < 4; ++w) {
                int i = t + w * 1024;
                int ixj = i ^ j;
                if (ixj > i) {
                    bool up = (i & k) == 0;
                    float h1 = sh[i], h2 = sh[ixj];
                    int i1 = si[i], i2 = si[ixj];
                    bool gt = (h1 > h2) || (h1 == h2 && i1 > i2);
                    if (gt == up) { sh[i] = h2; sh[ixj] = h1; si[i] = i2; si[ixj] = i1; }
                }
            }
            __syncthreads();
        }
        // local finish (j=2, j=1) in registers; direction uniform per chunk (k >= 8)
        float4 lh = *(const float4*)(sh + base);
        int4 li = *(const int4*)(si + base);
        h[0] = lh.x; h[1] = lh.y; h[2] = lh.z; h[3] = lh.w;
        id[0] = li.x; id[1] = li.y; id[2] = li.z; id[3] = li.w;
        bool up = (base & k) == 0;
        ce(h[0], id[0], h[2], id[2], up);
        ce(h[1], id[1], h[3], id[3], up);
        ce(h[0], id[0], h[1], id[1], up);
        ce(h[2], id[2], h[3], id[3], up);
        if (k == SEQ) {
            *(int4*)(dst + base) = make_int4(id[0], id[1], id[2], id[3]);
        } else {
            *(float4*)(sh + base) = make_float4(h[0], h[1], h[2], h[3]);
            *(int4*)(si + base) = make_int4(id[0], id[1], id[2], id[3]);
            __syncthreads();
        }
    }
}

// ---- pass 1: row logsumexp; Q frags in regs, K hi/lo in LDS (37.9 KB) ----
__global__ __launch_bounds__(512, 6) void lse_kernel(const float* __restrict__ q,
        const float* __restrict__ k, const int* __restrict__ qpos,
        const int* __restrict__ kpos, float* __restrict__ lse) {
    extern __shared__ char smem[];
    short* khi = (short*)smem;           // 128*72*2 = 18432 B
    short* klo = khi + 128*QS2;          // ends 36864
    int* qp = (int*)(smem + 36864);
    int* kp = qp + CL;                   // total 37888 B
    int blk = blockIdx.x;
    int c = blk & (NC-1);
    int hb = blk / NC;
    int b = hb & (BS-1);
    int t = threadIdx.x, lane = t & 63, w = t >> 6;
    int l15 = lane & 15, lg = lane >> 4;
    size_t posbase = (size_t)hb*SEQ + (size_t)c*CL;

    // Q fragments straight from global (own rows per wave); bit-identical split
    int qrow = qpos[posbase + w*16 + l15];
    const float* qsrc = q + ((size_t)b*SEQ + qrow)*DIM + lg*8;
    float4 qv0 = *(const float4*)(qsrc);
    float4 qv1 = *(const float4*)(qsrc + 4);
    float4 qv2 = *(const float4*)(qsrc + 32);
    float4 qv3 = *(const float4*)(qsrc + 36);

    if (t < CL) qp[t] = qpos[posbase + t];
    else if (t < 2*CL) kp[t - CL] = kpos[posbase + (t - CL)];
    __syncthreads();
    for (int task = t; task < 2048; task += 512) {
        int r = task >> 4, d4 = task & 15;
        float4 vv = ((const float4*)(k + ((size_t)b*SEQ + kp[r])*DIM))[d4];
        ushort4 h, l;
        h.x = f2bf(vv.x); h.y = f2bf(vv.y); h.z = f2bf(vv.z); h.w = f2bf(vv.w);
        l.x = f2bf(vv.x - bf2f(h.x)); l.y = f2bf(vv.y - bf2f(h.y));
        l.z = f2bf(vv.z - bf2f(h.z)); l.w = f2bf(vv.w - bf2f(h.w));
        *(ushort4*)(khi + r*QS2 + d4*4) = h;
        *(ushort4*)(klo + r*QS2 + d4*4) = l;
    }
    bf8_t ah[2], al[2];
    split8(qv0, qv1, ah[0], al[0]);
    split8(qv2, qv3, ah[1], al[1]);
    __syncthreads();
    f4_t acc[8] = {};
    #pragma unroll
    for (int ks = 0; ks < 2; ++ks) {
        #pragma unroll
        for (int ct = 0; ct < 8; ++ct) {
            int brow = (ct*16 + l15)*QS2 + lg*8 + 32*ks;
            bf8_t bh = *(bf8_t*)(khi + brow);
            bf8_t bl = *(bf8_t*)(klo + brow);
            acc[ct] = __builtin_amdgcn_mfma_f32_16x16x32_bf16(ah[ks], bh, acc[ct], 0, 0, 0);
            acc[ct] = __builtin_amdgcn_mfma_f32_16x16x32_bf16(al[ks], bh, acc[ct], 0, 0, 0);
            acc[ct] = __builtin_amdgcn_mfma_f32_16x16x32_bf16(ah[ks], bl, acc[ct], 0, 0, 0);
        }
    }
    // row-reduce: row = w*16 + lg*4 + r lives across the 16-lane group
    #pragma unroll
    for (int r = 0; r < 4; ++r) {
        float m = acc[0][r];
        #pragma unroll
        for (int ct = 1; ct < 8; ++ct) m = fmaxf(m, acc[ct][r]);
        m = fmaxf(m, __shfl_xor(m, 1)); m = fmaxf(m, __shfl_xor(m, 2));
        m = fmaxf(m, __shfl_xor(m, 4)); m = fmaxf(m, __shfl_xor(m, 8));
        float s = 0.f;
        #pragma unroll
        for (int ct = 0; ct < 8; ++ct) s += __expf(acc[ct][r] - m);
        s += __shfl_xor(s, 1); s += __shfl_xor(s, 2);
        s += __shfl_xor(s, 4); s += __shfl_xor(s, 8);
        if (l15 == 0) lse[(size_t)hb*SEQ + qp[w*16 + lg*4 + r]] = m + __logf(s);
    }
}

// ---------------- Z = logsumexp over hash rounds ----------------
__global__ __launch_bounds__(256) void z_kernel(const float* __restrict__ lse,
        float* __restrict__ Z) {
    int i = blockIdx.x * 256 + threadIdx.x;
    float vals[NH];
    float m = -1e30f;
    #pragma unroll
    for (int h = 0; h < NH; ++h) {
        vals[h] = lse[(size_t)h*BS*SEQ + i];
        m = fmaxf(m, vals[h]);
    }
    float s = 0.f;
    #pragma unroll
    for (int h = 0; h < NH; ++h) s += expf(vals[h] - m);
    Z[i] = m + logf(s);
}

// ---- pass 2: exp(QK^T - Z) @ V via MFMA; 38.4 KB LDS, halved-P PV ----
__global__ __launch_bounds__(512, 6) void attn_kernel(const float* __restrict__ q,
        const float* __restrict__ k, const float* __restrict__ v,
        const int* __restrict__ qpos, const int* __restrict__ kpos,
        const float* __restrict__ Z, float* __restrict__ out) {
    extern __shared__ char smem[];
    short* khi = (short*)smem;           // QK phase: 36864 B
    short* klo = khi + 128*QS2;
    short* vt = (short*)smem;            // PV overlay: 64 x VS2 x2 = 17408 B
    short* pb = (short*)(smem + 17408);  // 128 x PS x2 = 18432 B (ends 35840)
    int* qp = (int*)(smem + 36864);      // persistent tail
    int* kp = qp + CL;
    float* zq = (float*)(kp + CL);       // total 38400 B
    int blk = blockIdx.x;
    int c = blk & (NC-1);
    int hb = blk / NC;
    int b = hb & (BS-1);
    int t = threadIdx.x, lane = t & 63, w = t >> 6;
    int l15 = lane & 15, lg = lane >> 4;
    size_t posbase = (size_t)hb*SEQ + (size_t)c*CL;

    // Q fragments straight from global (no Q LDS tile)
    int qrow = qpos[posbase + w*16 + l15];
    const float* qsrc = q + ((size_t)b*SEQ + qrow)*DIM + lg*8;
    float4 qv0 = *(const float4*)(qsrc);
    float4 qv1 = *(const float4*)(qsrc + 4);
    float4 qv2 = *(const float4*)(qsrc + 32);
    float4 qv3 = *(const float4*)(qsrc + 36);

    if (t < CL) qp[t] = qpos[posbase + t];
    else if (t < 2*CL) kp[t - CL] = kpos[posbase + (t - CL)];
    __syncthreads();
    if (t < CL) zq[t] = Z[(size_t)b*SEQ + qp[t]];
    for (int task = t; task < 2048; task += 512) {
        int r = task >> 4, d4 = task & 15;
        float4 vv = ((const float4*)(k + ((size_t)b*SEQ + kp[r])*DIM))[d4];
        ushort4 h, l;
        h.x = f2bf(vv.x); h.y = f2bf(vv.y); h.z = f2bf(vv.z); h.w = f2bf(vv.w);
        l.x = f2bf(vv.x - bf2f(h.x)); l.y = f2bf(vv.y - bf2f(h.y));
        l.z = f2bf(vv.z - bf2f(h.z)); l.w = f2bf(vv.w - bf2f(h.w));
        *(ushort4*)(khi + r*QS2 + d4*4) = h;
        *(ushort4*)(klo + r*QS2 + d4*4) = l;
    }
    bf8_t ah[2], al[2];
    split8(qv0, qv1, ah[0], al[0]);
    split8(qv2, qv3, ah[1], al[1]);
    __syncthreads();
    f4_t acc[8] = {};
    #pragma unroll
    for (int ks = 0; ks < 2; ++ks) {
        #pragma unroll
        for (int ct = 0; ct < 8; ++ct) {
            int brow = (ct*16 + l15)*QS2 + lg*8 + 32*ks;
            bf8_t bh = *(bf8_t*)(khi + brow);
            bf8_t bl = *(bf8_t*)(klo + brow);
            acc[ct] = __builtin_amdgcn_mfma_f32_16x16x32_bf16(ah[ks], bh, acc[ct], 0, 0, 0);
            acc[ct] = __builtin_amdgcn_mfma_f32_16x16x32_bf16(al[ks], bh, acc[ct], 0, 0, 0);
            acc[ct] = __builtin_amdgcn_mfma_f32_16x16x32_bf16(ah[ks], bl, acc[ct], 0, 0, 0);
        }
    }
    // P = exp(inner - Z) in place (C/D: col = l15+16ct, row = w*16+lg*4+r)
    {
        float zr[4];
        #pragma unroll
        for (int r = 0; r < 4; ++r) zr[r] = zq[w*16 + lg*4 + r];
        #pragma unroll
        for (int ct = 0; ct < 8; ++ct)
            #pragma unroll
            for (int r = 0; r < 4; ++r)
                acc[ct][r] = __expf(acc[ct][r] - zr[r]);
    }
    __syncthreads();   // K LDS tiles dead; overlay becomes valid
    // V gather (rows wave-uniform via kp, lane = output dim d)
    float vr0[8], vr1[8];
    #pragma unroll
    for (int j = 0; j < 8; ++j) {
        int r0 = kp[w*8 + j];
        int r1 = kp[(w+8)*8 + j];
        vr0[j] = v[((size_t)b*SEQ + r0)*DIM + lane];
        vr1[j] = v[((size_t)b*SEQ + r1)*DIM + lane];
    }
    // P half 0 (k-cols 0..63) while V loads are in flight
    #pragma unroll
    for (int ct = 0; ct < 4; ++ct)
        #pragma unroll
        for (int r = 0; r < 4; ++r)
            pb[(w*16 + lg*4 + r)*PS + ct*16 + l15] = (short)f2bf(acc[ct][r]);
    // Vt write (transposed, bf16)
    {
        bf8_t pk0, pk1;
        #pragma unroll
        for (int j = 0; j < 8; ++j) { pk0[j] = (short)f2bf(vr0[j]); pk1[j] = (short)f2bf(vr1[j]); }
        *(bf8_t*)(vt + lane*VS2 + w*8)     = pk0;
        *(bf8_t*)(vt + lane*VS2 + (w+8)*8) = pk1;
    }
    __syncthreads();
    f4_t oacc[4] = {};
    #pragma unroll
    for (int ks = 0; ks < 2; ++ks) {
        bf8_t pa = *(bf8_t*)(pb + (w*16 + l15)*PS + ks*32 + lg*8);
        #pragma unroll
        for (int n = 0; n < 4; ++n) {
            bf8_t vb = *(bf8_t*)(vt + (n*16 + l15)*VS2 + ks*32 + lg*8);
            oacc[n] = __builtin_amdgcn_mfma_f32_16x16x32_bf16(pa, vb, oacc[n], 0, 0, 0);
        }
    }
    __syncthreads();   // pb half 0 consumed
    // P half 1 (k-cols 64..127)
    #pragma unroll
    for (int ct = 4; ct < 8; ++ct)
        #pragma unroll
        for (int r = 0; r < 4; ++r)
            pb[(w*16 + lg*4 + r)*PS + (ct-4)*16 + l15] = (short)f2bf(acc[ct][r]);
    __syncthreads();
    #pragma unroll
    for (int ks = 2; ks < 4; ++ks) {
        bf8_t pa = *(bf8_t*)(pb + (w*16 + l15)*PS + (ks-2)*32 + lg*8);
        #pragma unroll
        for (int n = 0; n < 4; ++n) {
            bf8_t vb = *(bf8_t*)(vt + (n*16 + l15)*VS2 + ks*32 + lg*8);
            oacc[n] = __builtin_amdgcn_mfma_f32_16x16x32_bf16(pa, vb, oacc[n], 0, 0, 0);
        }
    }
    #pragma unroll
    for (int n = 0; n < 4; ++n)
        #pragma unroll
        for (int r = 0; r < 4; ++r) {
            int row = w*16 + lg*4 + r;
            atomicAdd(out + ((size_t)b*SEQ + qp[row])*DIM + n*16 + l15, oacc[n][r]);
        }
}

extern "C" void kernel_launch(void* const* d_in, const int* in_sizes, int n_in,
                              void* d_out, int out_size, void* d_ws, size_t ws_size,
                              hipStream_t stream) {
    const float* q     = (const float*)d_in[0];
    const float* k     = (const float*)d_in[1];
    const float* v     = (const float*)d_in[2];
    const float* alpha = (const float*)d_in[3];
    const float* beta  = (const float*)d_in[4];
    float* out = (float*)d_out;

    float* ws   = (float*)d_ws;
    float* M2   = ws;                        // 16 (padded to 64)
    float* qn2  = ws + 64;                   // BS*SEQ
    float* kn2  = qn2 + BS*SEQ;              // BS*SEQ
    float* qh   = kn2 + BS*SEQ;              // NH*BS*SEQ
    float* kh   = qh + (size_t)NH*BS*SEQ;    // NH*BS*SEQ
    int*   qpos = (int*)(kh + (size_t)NH*BS*SEQ);  // NH*BS*SEQ
    int*   kpos = qpos + (size_t)NH*BS*SEQ;        // NH*BS*SEQ
    float* lse  = (float*)(kpos + (size_t)NH*BS*SEQ); // NH*BS*SEQ
    float* Z    = lse + (size_t)NH*BS*SEQ;         // BS*SEQ

    hipMemsetAsync(M2, 0, 64*sizeof(float), stream);
    hipMemsetAsync(out, 0, (size_t)out_size*sizeof(float), stream);

    norms_kernel<<<2*BS*SEQ/64, 256, 0, stream>>>(q, k, qn2, kn2, (unsigned int*)M2);
    hash_kernel<<<BS*SEQ/64, 256, 0, stream>>>(q, k, qn2, kn2, (const unsigned int*)M2,
                                               alpha, beta, qh, kh);
    sort_kernel<<<2*NPAIR, 1024, 0, stream>>>(qh, kh, qpos, kpos);

    const int lse_lds  = 36864 + 2*CL*(int)sizeof(int);                         // 37888 B
    const int attn_lds = 36864 + 2*CL*(int)sizeof(int) + CL*(int)sizeof(float); // 38400 B
    lse_kernel<<<NH*BS*NC, 512, lse_lds, stream>>>(q, k, qpos, kpos, lse);
    z_kernel<<<BS*SEQ/256, 256, 0, stream>>>(lse, Z);
    attn_kernel<<<NH*BS*NC, 512, attn_lds, stream>>>(q, k, v, qpos, kpos, Z, out);
}

// Round 12
// 349.009 us; speedup vs baseline: 3.2588x; 1.0581x over previous
//
#include <hip/hip_runtime.h>
#include <hip/hip_bf16.h>

#define BS 16
#define SEQ 4096
#define DIM 64
#define NH 8
#define CL 128
#define NC (SEQ/CL)       // 32
#define NPAIR (NH*BS)     // 128
#define QS2 72            // bf16 LDS row stride for K tiles (144 B, 16B-aligned)
#define VS2 136           // bf16 LDS row stride for Vt (272 B, 16B-aligned)
#define PS 72             // bf16 LDS row stride for P half-buffer (fallback attn)
#define PSD 136           // bf16 LDS row stride for full-P overlay in lse_p

typedef __attribute__((ext_vector_type(8))) short bf8_t;   // 8 bf16 (4 VGPR)
typedef __attribute__((ext_vector_type(4))) float f4_t;    // MFMA C/D

__device__ __forceinline__ unsigned short f2bf(float x) {
    union { float f; unsigned u; } a; a.f = x;
    unsigned r = a.u + 0x7FFF + ((a.u >> 16) & 1);
    return (unsigned short)(r >> 16);
}
__device__ __forceinline__ float bf2f(unsigned short h) {
    union { unsigned u; float f; } a; a.u = ((unsigned)h) << 16; return a.f;
}
__device__ __forceinline__ void split8(float4 a, float4 b, bf8_t& hi, bf8_t& lo) {
    float v[8] = {a.x, a.y, a.z, a.w, b.x, b.y, b.z, b.w};
    #pragma unroll
    for (int j = 0; j < 8; ++j) {
        unsigned short h = f2bf(v[j]);
        hi[j] = (short)h;
        lo[j] = (short)f2bf(v[j] - bf2f(h));
    }
}

// ---------------- norms + per-batch max(norm^2) ----------------
__global__ __launch_bounds__(256) void norms_kernel(const float* __restrict__ q,
        const float* __restrict__ k, float* __restrict__ qn2, float* __restrict__ kn2,
        unsigned int* __restrict__ M2bits) {
    int blk = blockIdx.x;
    const int qblocks = BS*SEQ/64;
    bool is_q = blk < qblocks;
    int rowbase = (is_q ? blk : blk - qblocks) * 64;
    const float* src = is_q ? q : k;
    float* dst = is_q ? qn2 : kn2;
    int t = threadIdx.x;
    int sub = t & 3;
    int r = rowbase + (t >> 2);
    const float4* row4 = (const float4*)(src + (size_t)r*DIM) + sub*4;
    float s = 0.f;
    #pragma unroll
    for (int c2 = 0; c2 < 4; ++c2) {
        float4 vv = row4[c2];
        s += vv.x*vv.x + vv.y*vv.y + vv.z*vv.z + vv.w*vv.w;
    }
    s += __shfl_xor(s, 1);
    s += __shfl_xor(s, 2);
    if (sub == 0) dst[r] = s;
    __shared__ float red[256];
    red[t] = s;
    __syncthreads();
    #pragma unroll
    for (int o = 128; o > 0; o >>= 1) {
        if (t < o) red[t] = fmaxf(red[t], red[t + o]);
        __syncthreads();
    }
    if (t == 0) atomicMax(&M2bits[r / SEQ], __float_as_uint(red[0]));
}

// ---------------- E2LSH hashes ----------------
__global__ __launch_bounds__(256) void hash_kernel(const float* __restrict__ q,
        const float* __restrict__ k, const float* __restrict__ qn2,
        const float* __restrict__ kn2, const unsigned int* __restrict__ M2bits,
        const float* __restrict__ alpha, const float* __restrict__ beta,
        float* __restrict__ qh, float* __restrict__ kh) {
    int t = threadIdx.x;
    int sub = t & 3;
    int r = blockIdx.x * 64 + (t >> 2);
    const float4* q4 = (const float4*)(q + (size_t)r*DIM) + sub*4;
    const float4* k4 = (const float4*)(k + (size_t)r*DIM) + sub*4;
    float qa[NH], ka[NH];
    #pragma unroll
    for (int h = 0; h < NH; ++h) { qa[h] = 0.f; ka[h] = 0.f; }
    #pragma unroll
    for (int c2 = 0; c2 < 4; ++c2) {
        int d0 = sub*16 + c2*4;
        float4 qv = q4[c2], kv = k4[c2];
        #pragma unroll
        for (int h = 0; h < NH; ++h) {
            float a0 = alpha[(d0+0)*NH+h], a1 = alpha[(d0+1)*NH+h];
            float a2 = alpha[(d0+2)*NH+h], a3 = alpha[(d0+3)*NH+h];
            qa[h] += qv.x*a0 + qv.y*a1 + qv.z*a2 + qv.w*a3;
            ka[h] += kv.x*a0 + kv.y*a1 + kv.z*a2 + kv.w*a3;
        }
    }
    #pragma unroll
    for (int h = 0; h < NH; ++h) {
        qa[h] += __shfl_xor(qa[h], 1); qa[h] += __shfl_xor(qa[h], 2);
        ka[h] += __shfl_xor(ka[h], 1); ka[h] += __shfl_xor(ka[h], 2);
    }
    if (sub == 0) {
        int b = r / SEQ;
        float m2 = __uint_as_float(M2bits[b]);
        float qe = sqrtf(fmaxf(m2 - qn2[r], 0.f));
        float ke = sqrtf(fmaxf(m2 - kn2[r], 0.f));
        #pragma unroll
        for (int h = 0; h < NH; ++h) {
            qh[(size_t)h*BS*SEQ + r] = qa[h] + qe*alpha[DIM*NH + h] + beta[h];
            kh[(size_t)h*BS*SEQ + r] = ka[h] + ke*alpha[(DIM+1)*NH + h] + beta[h];
        }
    }
}

// ---- stable bitonic argsort v4: shuffle steps for j<=128, LDS only j>=256 ----
__device__ __forceinline__ void ce(float& h1, int& i1, float& h2, int& i2, bool up) {
    bool gt = (h1 > h2) || (h1 == h2 && i1 > i2);
    if (gt == up) {
        float th = h1; h1 = h2; h2 = th;
        int ti = i1; i1 = i2; i2 = ti;
    }
}

__device__ __forceinline__ void shstep(float h[4], int id[4], int base, int k, int j) {
    int lx = j >> 2;                    // partner lane xor (1..32), within wave
    bool meLower = (base & j) == 0;
    bool up = (base & k) == 0;
    #pragma unroll
    for (int e = 0; e < 4; ++e) {
        float hp = __shfl_xor(h[e], lx);
        int ip = __shfl_xor(id[e], lx);
        float hl = meLower ? h[e] : hp;  int il = meLower ? id[e] : ip;
        float hu = meLower ? hp : h[e];  int iu = meLower ? ip : id[e];
        bool gt = (hl > hu) || (hl == hu && il > iu);
        bool sw = (gt == up);
        h[e] = sw ? hp : h[e];
        id[e] = sw ? ip : id[e];
    }
}

__global__ __launch_bounds__(1024) void sort_kernel(const float* __restrict__ qh,
        const float* __restrict__ kh, int* __restrict__ qpos, int* __restrict__ kpos) {
    __shared__ float sh[SEQ];
    __shared__ int si[SEQ];
    int blk = blockIdx.x;
    const float* src; int* dst;
    if (blk < NPAIR) { src = qh + (size_t)blk*SEQ; dst = qpos + (size_t)blk*SEQ; }
    else { src = kh + (size_t)(blk - NPAIR)*SEQ; dst = kpos + (size_t)(blk - NPAIR)*SEQ; }
    int t = threadIdx.x;
    int base = t * 4;

    float4 hv = *(const float4*)(src + base);
    float h[4] = {hv.x, hv.y, hv.z, hv.w};
    int id[4] = {base, base + 1, base + 2, base + 3};
    // k=2, k=4 fully in-thread
    ce(h[0], id[0], h[1], id[1], true);
    ce(h[2], id[2], h[3], id[3], false);
    bool up4 = (base & 4) == 0;
    ce(h[0], id[0], h[2], id[2], up4);
    ce(h[1], id[1], h[3], id[3], up4);
    ce(h[0], id[0], h[1], id[1], up4);
    ce(h[2], id[2], h[3], id[3], up4);

    // k = 8..256: all cross-thread steps via wave shuffles (no barriers)
    for (int k = 8; k <= 256; k <<= 1) {
        for (int j = k >> 1; j >= 4; j >>= 1) shstep(h, id, base, k, j);
        bool up = (base & k) == 0;
        ce(h[0], id[0], h[2], id[2], up);
        ce(h[1], id[1], h[3], id[3], up);
        ce(h[0], id[0], h[1], id[1], up);
        ce(h[2], id[2], h[3], id[3], up);
    }

    // k = 512..4096: j>=256 in LDS, then j<=128 shuffles, j<=2 in-thread
    for (int k = 512; k <= SEQ; k <<= 1) {
        *(float4*)(sh + base) = make_float4(h[0], h[1], h[2], h[3]);
        *(int4*)(si + base) = make_int4(id[0], id[1], id[2], id[3]);
        __syncthreads();
        for (int j = k >> 1; j >= 256; j >>= 1) {
            #pragma unroll
            for (int w2 = 0; w2 < 2; ++w2) {
                int idx = t + w2 * 1024;
                int i = ((idx & ~(j - 1)) << 1) | (idx & (j - 1));
                int ix = i + j;
                bool up = (i & k) == 0;
                float h1 = sh[i], h2 = sh[ix];
                int i1 = si[i], i2 = si[ix];
                bool gt = (h1 > h2) || (h1 == h2 && i1 > i2);
                if (gt == up) { sh[i] = h2; sh[ix] = h1; si[i] = i2; si[ix] = i1; }
            }
            __syncthreads();
        }
        float4 lh = *(const float4*)(sh + base);
        int4 li = *(const int4*)(si + base);
        h[0] = lh.x; h[1] = lh.y; h[2] = lh.z; h[3] = lh.w;
        id[0] = li.x; id[1] = li.y; id[2] = li.z; id[3] = li.w;
        for (int j = 128; j >= 4; j >>= 1) shstep(h, id, base, k, j);
        bool up = (base & k) == 0;
        ce(h[0], id[0], h[2], id[2], up);
        ce(h[1], id[1], h[3], id[3], up);
        ce(h[0], id[0], h[1], id[1], up);
        ce(h[2], id[2], h[3], id[3], up);
    }
    *(int4*)(dst + base) = make_int4(id[0], id[1], id[2], id[3]);
}

// ---- pass 1 (fallback): row logsumexp only ----
__global__ __launch_bounds__(512, 6) void lse_kernel(const float* __restrict__ q,
        const float* __restrict__ k, const int* __restrict__ qpos,
        const int* __restrict__ kpos, float* __restrict__ lse) {
    extern __shared__ char smem[];
    short* khi = (short*)smem;
    short* klo = khi + 128*QS2;
    int* qp = (int*)(smem + 36864);
    int* kp = qp + CL;
    int blk = blockIdx.x;
    int c = blk & (NC-1);
    int hb = blk / NC;
    int b = hb & (BS-1);
    int t = threadIdx.x, lane = t & 63, w = t >> 6;
    int l15 = lane & 15, lg = lane >> 4;
    size_t posbase = (size_t)hb*SEQ + (size_t)c*CL;

    int qrow = qpos[posbase + w*16 + l15];
    const float* qsrc = q + ((size_t)b*SEQ + qrow)*DIM + lg*8;
    float4 qv0 = *(const float4*)(qsrc);
    float4 qv1 = *(const float4*)(qsrc + 4);
    float4 qv2 = *(const float4*)(qsrc + 32);
    float4 qv3 = *(const float4*)(qsrc + 36);

    if (t < CL) qp[t] = qpos[posbase + t];
    else if (t < 2*CL) kp[t - CL] = kpos[posbase + (t - CL)];
    __syncthreads();
    for (int task = t; task < 2048; task += 512) {
        int r = task >> 4, d4 = task & 15;
        float4 vv = ((const float4*)(k + ((size_t)b*SEQ + kp[r])*DIM))[d4];
        ushort4 h, l;
        h.x = f2bf(vv.x); h.y = f2bf(vv.y); h.z = f2bf(vv.z); h.w = f2bf(vv.w);
        l.x = f2bf(vv.x - bf2f(h.x)); l.y = f2bf(vv.y - bf2f(h.y));
        l.z = f2bf(vv.z - bf2f(h.z)); l.w = f2bf(vv.w - bf2f(h.w));
        *(ushort4*)(khi + r*QS2 + d4*4) = h;
        *(ushort4*)(klo + r*QS2 + d4*4) = l;
    }
    bf8_t ah[2], al[2];
    split8(qv0, qv1, ah[0], al[0]);
    split8(qv2, qv3, ah[1], al[1]);
    __syncthreads();
    f4_t acc[8] = {};
    #pragma unroll
    for (int ks = 0; ks < 2; ++ks) {
        #pragma unroll
        for (int ct = 0; ct < 8; ++ct) {
            int brow = (ct*16 + l15)*QS2 + lg*8 + 32*ks;
            bf8_t bh = *(bf8_t*)(khi + brow);
            bf8_t bl = *(bf8_t*)(klo + brow);
            acc[ct] = __builtin_amdgcn_mfma_f32_16x16x32_bf16(ah[ks], bh, acc[ct], 0, 0, 0);
            acc[ct] = __builtin_amdgcn_mfma_f32_16x16x32_bf16(al[ks], bh, acc[ct], 0, 0, 0);
            acc[ct] = __builtin_amdgcn_mfma_f32_16x16x32_bf16(ah[ks], bl, acc[ct], 0, 0, 0);
        }
    }
    #pragma unroll
    for (int r = 0; r < 4; ++r) {
        float m = acc[0][r];
        #pragma unroll
        for (int ct = 1; ct < 8; ++ct) m = fmaxf(m, acc[ct][r]);
        m = fmaxf(m, __shfl_xor(m, 1)); m = fmaxf(m, __shfl_xor(m, 2));
        m = fmaxf(m, __shfl_xor(m, 4)); m = fmaxf(m, __shfl_xor(m, 8));
        float s = 0.f;
        #pragma unroll
        for (int ct = 0; ct < 8; ++ct) s += __expf(acc[ct][r] - m);
        s += __shfl_xor(s, 1); s += __shfl_xor(s, 2);
        s += __shfl_xor(s, 4); s += __shfl_xor(s, 8);
        if (l15 == 0) lse[(size_t)hb*SEQ + qp[w*16 + lg*4 + r]] = m + __logf(s);
    }
}

// ---- pass 1 (fused): logsumexp + P = exp(inner - m) cached to workspace ----
__global__ __launch_bounds__(512, 6) void lse_p_kernel(const float* __restrict__ q,
        const float* __restrict__ k, const int* __restrict__ qpos,
        const int* __restrict__ kpos, float* __restrict__ lse,
        float* __restrict__ mbuf, unsigned short* __restrict__ Pg) {
    extern __shared__ char smem[];
    short* khi = (short*)smem;           // QK phase: 36864 B
    short* klo = khi + 128*QS2;
    short* pb = (short*)smem;            // overlay: 128 x PSD x2 = 34816 B
    int* qp = (int*)(smem + 36864);
    int* kp = qp + CL;
    int blk = blockIdx.x;
    int c = blk & (NC-1);
    int hb = blk / NC;
    int b = hb & (BS-1);
    int t = threadIdx.x, lane = t & 63, w = t >> 6;
    int l15 = lane & 15, lg = lane >> 4;
    size_t posbase = (size_t)hb*SEQ + (size_t)c*CL;

    int qrow = qpos[posbase + w*16 + l15];
    const float* qsrc = q + ((size_t)b*SEQ + qrow)*DIM + lg*8;
    float4 qv0 = *(const float4*)(qsrc);
    float4 qv1 = *(const float4*)(qsrc + 4);
    float4 qv2 = *(const float4*)(qsrc + 32);
    float4 qv3 = *(const float4*)(qsrc + 36);

    if (t < CL) qp[t] = qpos[posbase + t];
    else if (t < 2*CL) kp[t - CL] = kpos[posbase + (t - CL)];
    __syncthreads();
    for (int task = t; task < 2048; task += 512) {
        int r = task >> 4, d4 = task & 15;
        float4 vv = ((const float4*)(k + ((size_t)b*SEQ + kp[r])*DIM))[d4];
        ushort4 h, l;
        h.x = f2bf(vv.x); h.y = f2bf(vv.y); h.z = f2bf(vv.z); h.w = f2bf(vv.w);
        l.x = f2bf(vv.x - bf2f(h.x)); l.y = f2bf(vv.y - bf2f(h.y));
        l.z = f2bf(vv.z - bf2f(h.z)); l.w = f2bf(vv.w - bf2f(h.w));
        *(ushort4*)(khi + r*QS2 + d4*4) = h;
        *(ushort4*)(klo + r*QS2 + d4*4) = l;
    }
    bf8_t ah[2], al[2];
    split8(qv0, qv1, ah[0], al[0]);
    split8(qv2, qv3, ah[1], al[1]);
    __syncthreads();
    f4_t acc[8] = {};
    #pragma unroll
    for (int ks = 0; ks < 2; ++ks) {
        #pragma unroll
        for (int ct = 0; ct < 8; ++ct) {
            int brow = (ct*16 + l15)*QS2 + lg*8 + 32*ks;
            bf8_t bh = *(bf8_t*)(khi + brow);
            bf8_t bl = *(bf8_t*)(klo + brow);
            acc[ct] = __builtin_amdgcn_mfma_f32_16x16x32_bf16(ah[ks], bh, acc[ct], 0, 0, 0);
            acc[ct] = __builtin_amdgcn_mfma_f32_16x16x32_bf16(al[ks], bh, acc[ct], 0, 0, 0);
            acc[ct] = __builtin_amdgcn_mfma_f32_16x16x32_bf16(ah[ks], bl, acc[ct], 0, 0, 0);
        }
    }
    #pragma unroll
    for (int r = 0; r < 4; ++r) {
        float m = acc[0][r];
        #pragma unroll
        for (int ct = 1; ct < 8; ++ct) m = fmaxf(m, acc[ct][r]);
        m = fmaxf(m, __shfl_xor(m, 1)); m = fmaxf(m, __shfl_xor(m, 2));
        m = fmaxf(m, __shfl_xor(m, 4)); m = fmaxf(m, __shfl_xor(m, 8));
        float s = 0.f;
        #pragma unroll
        for (int ct = 0; ct < 8; ++ct) {
            float p = __expf(acc[ct][r] - m);
            acc[ct][r] = p;
            s += p;
        }
        s += __shfl_xor(s, 1); s += __shfl_xor(s, 2);
        s += __shfl_xor(s, 4); s += __shfl_xor(s, 8);
        if (l15 == 0) {
            int row = w*16 + lg*4 + r;
            lse[(size_t)hb*SEQ + qp[row]] = m + __logf(s);
            mbuf[(size_t)hb*SEQ + c*CL + row] = m;
        }
    }
    __syncthreads();   // all waves done reading khi/klo; overlay becomes valid
    #pragma unroll
    for (int ct = 0; ct < 8; ++ct)
        #pragma unroll
        for (int r = 0; r < 4; ++r)
            pb[(w*16 + lg*4 + r)*PSD + ct*16 + l15] = (short)f2bf(acc[ct][r]);
    __syncthreads();
    size_t pbase = (size_t)blk << 14;   // 128*128 bf16 per cluster
    for (int task = t; task < 2048; task += 512) {
        int row = task >> 4, ch = task & 15;
        bf8_t vv2 = *(const bf8_t*)(pb + row*PSD + ch*8);
        *(bf8_t*)(Pg + pbase + row*128 + ch*8) = vv2;
    }
}

// ---------------- Z = logsumexp over hash rounds ----------------
__global__ __launch_bounds__(256) void z_kernel(const float* __restrict__ lse,
        float* __restrict__ Z) {
    int i = blockIdx.x * 256 + threadIdx.x;
    float vals[NH];
    float m = -1e30f;
    #pragma unroll
    for (int h = 0; h < NH; ++h) {
        vals[h] = lse[(size_t)h*BS*SEQ + i];
        m = fmaxf(m, vals[h]);
    }
    float s = 0.f;
    #pragma unroll
    for (int h = 0; h < NH; ++h) s += expf(vals[h] - m);
    Z[i] = m + logf(s);
}

// ---- pass 2 (fallback): full exp(QK^T - Z) @ V via MFMA ----
__global__ __launch_bounds__(512, 6) void attn_kernel(const float* __restrict__ q,
        const float* __restrict__ k, const float* __restrict__ v,
        const int* __restrict__ qpos, const int* __restrict__ kpos,
        const float* __restrict__ Z, float* __restrict__ out) {
    extern __shared__ char smem[];
    short* khi = (short*)smem;
    short* klo = khi + 128*QS2;
    short* vt = (short*)smem;
    short* pb = (short*)(smem + 17408);
    int* qp = (int*)(smem + 36864);
    int* kp = qp + CL;
    float* zq = (float*)(kp + CL);
    int blk = blockIdx.x;
    int c = blk & (NC-1);
    int hb = blk / NC;
    int b = hb & (BS-1);
    int t = threadIdx.x, lane = t & 63, w = t >> 6;
    int l15 = lane & 15, lg = lane >> 4;
    size_t posbase = (size_t)hb*SEQ + (size_t)c*CL;

    int qrow = qpos[posbase + w*16 + l15];
    const float* qsrc = q + ((size_t)b*SEQ + qrow)*DIM + lg*8;
    float4 qv0 = *(const float4*)(qsrc);
    float4 qv1 = *(const float4*)(qsrc + 4);
    float4 qv2 = *(const float4*)(qsrc + 32);
    float4 qv3 = *(const float4*)(qsrc + 36);

    if (t < CL) qp[t] = qpos[posbase + t];
    else if (t < 2*CL) kp[t - CL] = kpos[posbase + (t - CL)];
    __syncthreads();
    if (t < CL) zq[t] = Z[(size_t)b*SEQ + qp[t]];
    for (int task = t; task < 2048; task += 512) {
        int r = task >> 4, d4 = task & 15;
        float4 vv = ((const float4*)(k + ((size_t)b*SEQ + kp[r])*DIM))[d4];
        ushort4 h, l;
        h.x = f2bf(vv.x); h.y = f2bf(vv.y); h.z = f2bf(vv.z); h.w = f2bf(vv.w);
        l.x = f2bf(vv.x - bf2f(h.x)); l.y = f2bf(vv.y - bf2f(h.y));
        l.z = f2bf(vv.z - bf2f(h.z)); l.w = f2bf(vv.w - bf2f(h.w));
        *(ushort4*)(khi + r*QS2 + d4*4) = h;
        *(ushort4*)(klo + r*QS2 + d4*4) = l;
    }
    bf8_t ah[2], al[2];
    split8(qv0, qv1, ah[0], al[0]);
    split8(qv2, qv3, ah[1], al[1]);
    __syncthreads();
    f4_t acc[8] = {};
    #pragma unroll
    for (int ks = 0; ks < 2; ++ks) {
        #pragma unroll
        for (int ct = 0; ct < 8; ++ct) {
            int brow = (ct*16 + l15)*QS2 + lg*8 + 32*ks;
            bf8_t bh = *(bf8_t*)(khi + brow);
            bf8_t bl = *(bf8_t*)(klo + brow);
            acc[ct] = __builtin_amdgcn_mfma_f32_16x16x32_bf16(ah[ks], bh, acc[ct], 0, 0, 0);
            acc[ct] = __builtin_amdgcn_mfma_f32_16x16x32_bf16(al[ks], bh, acc[ct], 0, 0, 0);
            acc[ct] = __builtin_amdgcn_mfma_f32_16x16x32_bf16(ah[ks], bl, acc[ct], 0, 0, 0);
        }
    }
    {
        float zr[4];
        #pragma unroll
        for (int r = 0; r < 4; ++r) zr[r] = zq[w*16 + lg*4 + r];
        #pragma unroll
        for (int ct = 0; ct < 8; ++ct)
            #pragma unroll
            for (int r = 0; r < 4; ++r)
                acc[ct][r] = __expf(acc[ct][r] - zr[r]);
    }
    __syncthreads();
    float vr0[8], vr1[8];
    #pragma unroll
    for (int j = 0; j < 8; ++j) {
        int r0 = kp[w*8 + j];
        int r1 = kp[(w+8)*8 + j];
        vr0[j] = v[((size_t)b*SEQ + r0)*DIM + lane];
        vr1[j] = v[((size_t)b*SEQ + r1)*DIM + lane];
    }
    #pragma unroll
    for (int ct = 0; ct < 4; ++ct)
        #pragma unroll
        for (int r = 0; r < 4; ++r)
            pb[(w*16 + lg*4 + r)*PS + ct*16 + l15] = (short)f2bf(acc[ct][r]);
    {
        bf8_t pk0, pk1;
        #pragma unroll
        for (int j = 0; j < 8; ++j) { pk0[j] = (short)f2bf(vr0[j]); pk1[j] = (short)f2bf(vr1[j]); }
        *(bf8_t*)(vt + lane*VS2 + w*8)     = pk0;
        *(bf8_t*)(vt + lane*VS2 + (w+8)*8) = pk1;
    }
    __syncthreads();
    f4_t oacc[4] = {};
    #pragma unroll
    for (int ks = 0; ks < 2; ++ks) {
        bf8_t pa = *(bf8_t*)(pb + (w*16 + l15)*PS + ks*32 + lg*8);
        #pragma unroll
        for (int n = 0; n < 4; ++n) {
            bf8_t vb = *(bf8_t*)(vt + (n*16 + l15)*VS2 + ks*32 + lg*8);
            oacc[n] = __builtin_amdgcn_mfma_f32_16x16x32_bf16(pa, vb, oacc[n], 0, 0, 0);
        }
    }
    __syncthreads();
    #pragma unroll
    for (int ct = 4; ct < 8; ++ct)
        #pragma unroll
        for (int r = 0; r < 4; ++r)
            pb[(w*16 + lg*4 + r)*PS + (ct-4)*16 + l15] = (short)f2bf(acc[ct][r]);
    __syncthreads();
    #pragma unroll
    for (int ks = 2; ks < 4; ++ks) {
        bf8_t pa = *(bf8_t*)(pb + (w*16 + l15)*PS + (ks-2)*32 + lg*8);
        #pragma unroll
        for (int n = 0; n < 4; ++n) {
            bf8_t vb = *(bf8_t*)(vt + (n*16 + l15)*VS2 + ks*32 + lg*8);
            oacc[n] = __builtin_amdgcn_mfma_f32_16x16x32_bf16(pa, vb, oacc[n], 0, 0, 0);
        }
    }
    #pragma unroll
    for (int n = 0; n < 4; ++n)
        #pragma unroll
        for (int r = 0; r < 4; ++r) {
            int row = w*16 + lg*4 + r;
            atomicAdd(out + ((size_t)b*SEQ + qp[row])*DIM + n*16 + l15, oacc[n][r]);
        }
}

// ---- pass 2 (fused): PV only, P from workspace, rescale by exp(m - Z) ----
__global__ __launch_bounds__(512, 6) void attn_pv_kernel(const float* __restrict__ v,
        const int* __restrict__ qpos, const int* __restrict__ kpos,
        const float* __restrict__ Z, const float* __restrict__ mbuf,
        const unsigned short* __restrict__ Pg, float* __restrict__ out) {
    __shared__ short vt[64*VS2];          // 17408 B
    __shared__ int qp[CL], kp[CL];
    __shared__ float zq[CL], mq[CL];
    int blk = blockIdx.x;
    int c = blk & (NC-1);
    int hb = blk / NC;
    int b = hb & (BS-1);
    int t = threadIdx.x, lane = t & 63, w = t >> 6;
    int l15 = lane & 15, lg = lane >> 4;
    size_t posbase = (size_t)hb*SEQ + (size_t)c*CL;

    if (t < CL) qp[t] = qpos[posbase + t];
    else if (t < 2*CL) kp[t - CL] = kpos[posbase + (t - CL)];
    __syncthreads();
    if (t < CL) zq[t] = Z[(size_t)b*SEQ + qp[t]];
    else if (t < 2*CL) mq[t - CL] = mbuf[(size_t)hb*SEQ + c*CL + (t - CL)];
    // V gather (rows wave-uniform via kp, lane = output dim)
    float vr0[8], vr1[8];
    #pragma unroll
    for (int j = 0; j < 8; ++j) {
        int r0 = kp[w*8 + j];
        int r1 = kp[(w+8)*8 + j];
        vr0[j] = v[((size_t)b*SEQ + r0)*DIM + lane];
        vr1[j] = v[((size_t)b*SEQ + r1)*DIM + lane];
    }
    {
        bf8_t pk0, pk1;
        #pragma unroll
        for (int j = 0; j < 8; ++j) { pk0[j] = (short)f2bf(vr0[j]); pk1[j] = (short)f2bf(vr1[j]); }
        *(bf8_t*)(vt + lane*VS2 + w*8)     = pk0;
        *(bf8_t*)(vt + lane*VS2 + (w+8)*8) = pk1;
    }
    __syncthreads();
    size_t pbase = (size_t)blk << 14;
    f4_t oacc[4] = {};
    #pragma unroll
    for (int ks = 0; ks < 4; ++ks) {
        bf8_t pa = *(const bf8_t*)(Pg + pbase + (w*16 + l15)*128 + ks*32 + lg*8);
        #pragma unroll
        for (int n = 0; n < 4; ++n) {
            bf8_t vb = *(bf8_t*)(vt + (n*16 + l15)*VS2 + ks*32 + lg*8);
            oacc[n] = __builtin_amdgcn_mfma_f32_16x16x32_bf16(pa, vb, oacc[n], 0, 0, 0);
        }
    }
    float sc[4];
    #pragma unroll
    for (int r = 0; r < 4; ++r) {
        int row = w*16 + lg*4 + r;
        sc[r] = __expf(mq[row] - zq[row]);
    }
    #pragma unroll
    for (int n = 0; n < 4; ++n)
        #pragma unroll
        for (int r = 0; r < 4; ++r) {
            int row = w*16 + lg*4 + r;
            atomicAdd(out + ((size_t)b*SEQ + qp[row])*DIM + n*16 + l15, oacc[n][r]*sc[r]);
        }
}

extern "C" void kernel_launch(void* const* d_in, const int* in_sizes, int n_in,
                              void* d_out, int out_size, void* d_ws, size_t ws_size,
                              hipStream_t stream) {
    const float* q     = (const float*)d_in[0];
    const float* k     = (const float*)d_in[1];
    const float* v     = (const float*)d_in[2];
    const float* alpha = (const float*)d_in[3];
    const float* beta  = (const float*)d_in[4];
    float* out = (float*)d_out;

    float* ws   = (float*)d_ws;
    float* M2   = ws;                        // 64
    float* qn2  = ws + 64;                   // BS*SEQ
    float* kn2  = qn2 + BS*SEQ;
    float* qh   = kn2 + BS*SEQ;              // NH*BS*SEQ
    float* kh   = qh + (size_t)NH*BS*SEQ;
    int*   qpos = (int*)(kh + (size_t)NH*BS*SEQ);
    int*   kpos = qpos + (size_t)NH*BS*SEQ;
    float* lse  = (float*)(kpos + (size_t)NH*BS*SEQ);
    float* Z    = lse + (size_t)NH*BS*SEQ;   // BS*SEQ
    float* mbuf = Z + BS*SEQ;                // NH*BS*SEQ (fused path only)
    unsigned short* Pg = (unsigned short*)(mbuf + (size_t)NH*BS*SEQ);
    size_t p_bytes = (size_t)NH*BS*NC * CL * CL * sizeof(unsigned short); // 128 MiB
    size_t need = ((char*)Pg - (char*)d_ws) + p_bytes;
    bool fused = (ws_size >= need);

    hipMemsetAsync(M2, 0, 64*sizeof(float), stream);
    hipMemsetAsync(out, 0, (size_t)out_size*sizeof(float), stream);

    norms_kernel<<<2*BS*SEQ/64, 256, 0, stream>>>(q, k, qn2, kn2, (unsigned int*)M2);
    hash_kernel<<<BS*SEQ/64, 256, 0, stream>>>(q, k, qn2, kn2, (const unsigned int*)M2,
                                               alpha, beta, qh, kh);
    sort_kernel<<<2*NPAIR, 1024, 0, stream>>>(qh, kh, qpos, kpos);

    const int qk_lds = 36864 + 2*CL*(int)sizeof(int);                          // 37888 B
    if (fused) {
        lse_p_kernel<<<NH*BS*NC, 512, qk_lds, stream>>>(q, k, qpos, kpos, lse, mbuf, Pg);
        z_kernel<<<BS*SEQ/256, 256, 0, stream>>>(lse, Z);
        attn_pv_kernel<<<NH*BS*NC, 512, 0, stream>>>(v, qpos, kpos, Z, mbuf, Pg, out);
    } else {
        const int attn_lds = qk_lds + CL*(int)sizeof(float);                   // 38400 B
        lse_kernel<<<NH*BS*NC, 512, qk_lds, stream>>>(q, k, qpos, kpos, lse);
        z_kernel<<<BS*SEQ/256, 256, 0, stream>>>(lse, Z);
        attn_kernel<<<NH*BS*NC, 512, attn_lds, stream>>>(q, k, v, qpos, kpos, Z, out);
    }
}